// Round 1
// baseline (356.477 us; speedup 1.0000x reference)
//
#include <hip/hip_runtime.h>
#include <math.h>

// SupCR loss, MI355X. Round 1: correctness-first.
// Pipeline: prep (cf + sqnorms) -> fp32 tiled GEMM -> dist matrix (ws)
//           -> per-row: bitonic sort by dis, suffix log-sum-exp, tie fix via
//              lower_bound (== searchsorted side='left'), row value in double
//           -> final reduction to scalar loss.
// Log-space negative avoids the fp32 underflow of exp(-dist/0.07) (dist~32).

#define NN 2048      // N = B*V
#define BB 1024      // B
#define DD 512       // D
#define NT 256       // threads per block (4 waves)
#define EPT 8        // elements per thread in row kernel (NN/NT)
#define NEGINF (-INFINITY)

// ---------------- kernel 1: cf + squared norms ----------------
__global__ __launch_bounds__(256) void prep_kernel(const float* __restrict__ F,
                                                   float* __restrict__ cf,
                                                   float* __restrict__ sq) {
    __shared__ float red[NT];
    const int i = blockIdx.x;       // cf row
    const int t = threadIdx.x;
    const int b = i & (BB - 1);     // i % B
    const int v = i >> 10;          // i / B
    const float* src = F + (size_t)b * (2 * DD) + (size_t)v * DD;
    float ss = 0.f;
    for (int e = t; e < DD; e += NT) {
        float f = src[e];
        cf[(size_t)i * DD + e] = f;
        ss += f * f;
    }
    red[t] = ss;
    __syncthreads();
    for (int ofs = NT / 2; ofs > 0; ofs >>= 1) {
        if (t < ofs) red[t] += red[t + ofs];
        __syncthreads();
    }
    if (t == 0) sq[i] = red[0];
}

// ---------------- kernel 2: G = cf cf^T -> dist ----------------
#define TILE 64
#define BK 16
__global__ __launch_bounds__(256) void gemm_dist_kernel(const float* __restrict__ cf,
                                                        const float* __restrict__ sq,
                                                        float* __restrict__ dist) {
    __shared__ float As[BK][TILE];
    __shared__ float Bs[BK][TILE];
    const int tid = threadIdx.x;
    const int tx = tid & 15;
    const int ty = tid >> 4;
    const int row0 = blockIdx.y * TILE;
    const int col0 = blockIdx.x * TILE;

    float acc[4][4] = {};

    for (int k0 = 0; k0 < DD; k0 += BK) {
        // 64 rows x 16 k each for A and B tiles; 256 threads x 1 float4 each.
        {
            const int r = tid >> 2;        // 0..63
            const int kq = tid & 3;        // which float4 along k
            const float4 a = *reinterpret_cast<const float4*>(
                &cf[(size_t)(row0 + r) * DD + k0 + kq * 4]);
            As[kq * 4 + 0][r] = a.x; As[kq * 4 + 1][r] = a.y;
            As[kq * 4 + 2][r] = a.z; As[kq * 4 + 3][r] = a.w;
            const float4 bvec = *reinterpret_cast<const float4*>(
                &cf[(size_t)(col0 + r) * DD + k0 + kq * 4]);
            Bs[kq * 4 + 0][r] = bvec.x; Bs[kq * 4 + 1][r] = bvec.y;
            Bs[kq * 4 + 2][r] = bvec.z; Bs[kq * 4 + 3][r] = bvec.w;
        }
        __syncthreads();
        #pragma unroll
        for (int kk = 0; kk < BK; ++kk) {
            const float4 a4 = *reinterpret_cast<const float4*>(&As[kk][ty * 4]);
            const float4 b4 = *reinterpret_cast<const float4*>(&Bs[kk][tx * 4]);
            const float ar[4] = {a4.x, a4.y, a4.z, a4.w};
            const float br[4] = {b4.x, b4.y, b4.z, b4.w};
            #pragma unroll
            for (int r = 0; r < 4; ++r)
                #pragma unroll
                for (int c = 0; c < 4; ++c)
                    acc[r][c] = fmaf(ar[r], br[c], acc[r][c]);
        }
        __syncthreads();
    }

    const float4 sqj = *reinterpret_cast<const float4*>(&sq[col0 + tx * 4]);
    const float sj[4] = {sqj.x, sqj.y, sqj.z, sqj.w};
    #pragma unroll
    for (int r = 0; r < 4; ++r) {
        const int gi = row0 + ty * 4 + r;
        const float si = sq[gi];
        float4 o;
        float* op = &o.x;
        #pragma unroll
        for (int c = 0; c < 4; ++c) {
            float d2 = si + sj[c] - 2.f * acc[r][c];
            op[c] = (d2 > 0.f) ? sqrtf(d2) : 0.f;
        }
        *reinterpret_cast<float4*>(&dist[(size_t)gi * NN + col0 + tx * 4]) = o;
    }
}

// ---------------- kernel 3: per-row sorted suffix-LSE ----------------
__device__ __forceinline__ void lse_combine(float& m, float& s, float nm, float ns) {
    if (nm == NEGINF) return;
    if (m == NEGINF) { m = nm; s = ns; return; }
    if (nm <= m) { s += ns * expf(nm - m); }
    else         { s = ns + s * expf(m - nm); m = nm; }
}

__global__ __launch_bounds__(256) void row_kernel(const float* __restrict__ dist,
                                                  const float* __restrict__ labels,
                                                  double* __restrict__ rowval) {
    __shared__ float key[NN];
    __shared__ float val[NN];
    __shared__ float Ms[NN];
    __shared__ float Ss[NN];
    __shared__ float ctM[NT];
    __shared__ float ctS[NT];
    __shared__ double red[NT];

    const int i = blockIdx.x;
    const int t = threadIdx.x;
    const float lab_i = labels[i & (BB - 1)];
    const float negInvT = -1.0f / 0.07f;
    const float* drow = &dist[(size_t)i * NN];

    // load row: key = |lab_i - lab_j|, val = logits (diag -> -inf)
    double dsum = 0.0;
    for (int j = t; j < NN; j += NT) {
        const float d = drow[j];
        dsum += (double)d;
        key[j] = fabsf(lab_i - labels[j & (BB - 1)]);
        val[j] = (j == i) ? NEGINF : d * negInvT;
    }

    // bitonic sort (key asc, val rides along)
    for (int k = 2; k <= NN; k <<= 1) {
        for (int j = k >> 1; j > 0; j >>= 1) {
            __syncthreads();
            #pragma unroll
            for (int e = 0; e < EPT; ++e) {
                const int idx = t + e * NT;
                const int ixj = idx ^ j;
                if (ixj > idx) {
                    const float k1 = key[idx], k2 = key[ixj];
                    const bool up = ((idx & k) == 0);
                    if (up ? (k1 > k2) : (k1 < k2)) {
                        key[idx] = k2; key[ixj] = k1;
                        const float v1 = val[idx], v2 = val[ixj];
                        val[idx] = v2; val[ixj] = v1;
                    }
                }
            }
        }
    }
    __syncthreads();

    // chunk-local inclusive suffix LSE state (m, s)
    const int cb = t * EPT;
    {
        float m = NEGINF, s = 0.f;
        #pragma unroll
        for (int jj = EPT - 1; jj >= 0; --jj) {
            const float vv = val[cb + jj];
            if (vv != NEGINF) {
                if (m == NEGINF) { m = vv; s = 1.f; }
                else if (vv <= m) { s += expf(vv - m); }
                else { s = s * expf(m - vv) + 1.f; m = vv; }
            }
            Ms[cb + jj] = m;
            Ss[cb + jj] = s;
        }
        ctM[t] = m;
        ctS[t] = s;
    }
    __syncthreads();

    // inclusive suffix scan over the 256 chunk totals (Hillis-Steele)
    for (int st = 1; st < NT; st <<= 1) {
        float nm = NEGINF, ns = 0.f;
        if (t + st < NT) { nm = ctM[t + st]; ns = ctS[t + st]; }
        __syncthreads();
        float m = ctM[t], s = ctS[t];
        lse_combine(m, s, nm, ns);
        ctM[t] = m; ctS[t] = s;
        __syncthreads();
    }

    // full suffix LSE per position -> overwrite Ms with lse value
    {
        float tm = NEGINF, ts = 0.f;
        if (t + 1 < NT) { tm = ctM[t + 1]; ts = ctS[t + 1]; }
        #pragma unroll
        for (int jj = 0; jj < EPT; ++jj) {
            float m = Ms[cb + jj], s = Ss[cb + jj];
            lse_combine(m, s, tm, ts);
            Ms[cb + jj] = (m == NEGINF) ? NEGINF : (m + logf(s));
        }
    }
    __syncthreads();

    // tie fix: lower_bound of own key (== searchsorted side='left'), sum logs
    double lnsum = 0.0;
    #pragma unroll
    for (int jj = 0; jj < EPT; ++jj) {
        const float x = key[cb + jj];
        int lo = 0, hi = NN;
        while (lo < hi) {
            const int mid = (lo + hi) >> 1;
            if (key[mid] < x) lo = mid + 1; else hi = mid;
        }
        lnsum += (double)Ms[lo];
    }

    // block reductions (dsum, then lnsum)
    red[t] = dsum;
    __syncthreads();
    for (int ofs = NT / 2; ofs > 0; ofs >>= 1) {
        if (t < ofs) red[t] += red[t + ofs];
        __syncthreads();
    }
    const double total_d = red[0];
    __syncthreads();
    red[t] = lnsum;
    __syncthreads();
    for (int ofs = NT / 2; ofs > 0; ofs >>= 1) {
        if (t < ofs) red[t] += red[t + ofs];
        __syncthreads();
    }
    if (t == 0) {
        const double total_ln = red[0];
        const double lse_all = (double)Ms[0];  // diag's would-be log(negative)
        // sum_j logits - sum_{j!=i} log(negative)
        rowval[i] = (-total_d / 0.07) - (total_ln - lse_all);
    }
}

// ---------------- kernel 4: final mean ----------------
__global__ __launch_bounds__(256) void finalize_kernel(const double* __restrict__ rowval,
                                                       float* __restrict__ out) {
    __shared__ double red[NT];
    const int t = threadIdx.x;
    double s = 0.0;
    for (int j = t; j < NN; j += NT) s += rowval[j];
    red[t] = s;
    __syncthreads();
    for (int ofs = NT / 2; ofs > 0; ofs >>= 1) {
        if (t < ofs) red[t] += red[t + ofs];
        __syncthreads();
    }
    if (t == 0) {
        // loss = -(T/BT) * mean_i( rowval_i / (N-1) ),  T/BT = 1
        out[0] = (float)(-red[0] / ((double)NN * (double)(NN - 1)));
    }
}

extern "C" void kernel_launch(void* const* d_in, const int* in_sizes, int n_in,
                              void* d_out, int out_size, void* d_ws, size_t ws_size,
                              hipStream_t stream) {
    const float* features = (const float*)d_in[0];  // [1024, 2, 512] fp32
    const float* labels   = (const float*)d_in[1];  // [1024] fp32
    float* out = (float*)d_out;

    char* ws = (char*)d_ws;
    float*  cf     = (float*)ws;                                   // 4 MB
    float*  sq     = (float*)(ws + (size_t)4 * 1024 * 1024);       // 8 KB
    float*  dist   = (float*)(ws + (size_t)4 * 1024 * 1024 + 8192);// 16 MB
    double* rowval = (double*)(ws + (size_t)4 * 1024 * 1024 + 8192
                               + (size_t)NN * NN * sizeof(float)); // 16 KB

    prep_kernel<<<NN, NT, 0, stream>>>(features, cf, sq);
    dim3 ggrid(NN / TILE, NN / TILE);
    gemm_dist_kernel<<<ggrid, NT, 0, stream>>>(cf, sq, dist);
    row_kernel<<<NN, NT, 0, stream>>>(dist, labels, rowval);
    finalize_kernel<<<1, NT, 0, stream>>>(rowval, out);
}

// Round 2
// 230.716 us; speedup vs baseline: 1.5451x; 1.5451x over previous
//
#include <hip/hip_runtime.h>
#include <math.h>

// SupCR loss, MI355X. Round 2: kill the per-row bitonic sort.
// Labels are sorted ONCE (they're row-independent); along the sorted-label
// axis each row's keys |lab_i - lab_l| form an exact monotone valley, so the
// "negative" suffix-sum over key-sorted order == prefixLSE[L] + suffixLSE[R]
// with [L,R) the window {key < d} found by binary search on the rounded keys
// (bit-exact match to searchsorted side='left' tie semantics).
// GEMM emits dist with columns pre-permuted into sorted-label order.

#define NN 2048      // N = B*V
#define BB 1024      // B
#define DD 512       // D
#define NT 256       // threads per block
#define NEGINF (-INFINITY)

// ---------------- kernel 0: sort labels once ----------------
__global__ __launch_bounds__(256) void sort_labels_kernel(const float* __restrict__ labels,
                                                          float* __restrict__ slab,
                                                          int* __restrict__ sj,
                                                          int* __restrict__ inv) {
    __shared__ float kk[BB];
    __shared__ int   id[BB];
    const int t = threadIdx.x;
    #pragma unroll
    for (int e = 0; e < 4; ++e) { const int p = t + e * NT; kk[p] = labels[p]; id[p] = p; }
    for (int k = 2; k <= BB; k <<= 1) {
        for (int j = k >> 1; j > 0; j >>= 1) {
            __syncthreads();
            #pragma unroll
            for (int e = 0; e < 4; ++e) {
                const int idx = t + e * NT;
                const int ixj = idx ^ j;
                if (ixj > idx) {
                    const float k1 = kk[idx], k2 = kk[ixj];
                    const bool up = ((idx & k) == 0);
                    if (up ? (k1 > k2) : (k1 < k2)) {
                        kk[idx] = k2; kk[ixj] = k1;
                        const int i1 = id[idx]; id[idx] = id[ixj]; id[ixj] = i1;
                    }
                }
            }
        }
    }
    __syncthreads();
    #pragma unroll
    for (int e = 0; e < 4; ++e) {
        const int p = t + e * NT;
        const float lv = kk[p];
        const int b = id[p];
        // rows b and b+B share label lv; place them adjacent (ties, order free)
        slab[2 * p] = lv; slab[2 * p + 1] = lv;
        sj[2 * p] = b;    sj[2 * p + 1] = b + BB;
        inv[b] = 2 * p;   inv[b + BB] = 2 * p + 1;
    }
}

// ---------------- kernel 1: cf + squared norms ----------------
__global__ __launch_bounds__(256) void prep_kernel(const float* __restrict__ F,
                                                   float* __restrict__ cf,
                                                   float* __restrict__ sq) {
    __shared__ float red[NT];
    const int i = blockIdx.x;
    const int t = threadIdx.x;
    const int b = i & (BB - 1);
    const int v = i >> 10;
    const float* src = F + (size_t)b * (2 * DD) + (size_t)v * DD;
    float ss = 0.f;
    for (int e = t; e < DD; e += NT) {
        const float f = src[e];
        cf[(size_t)i * DD + e] = f;
        ss += f * f;
    }
    red[t] = ss;
    __syncthreads();
    for (int ofs = NT / 2; ofs > 0; ofs >>= 1) {
        if (t < ofs) red[t] += red[t + ofs];
        __syncthreads();
    }
    if (t == 0) sq[i] = red[0];
}

// ---------------- kernel 2: dist (columns permuted to sorted-label order) --
#define TILE 64
#define BK 16
__global__ __launch_bounds__(256) void gemm_dist_kernel(const float* __restrict__ cf,
                                                        const float* __restrict__ sq,
                                                        const int* __restrict__ sj,
                                                        float* __restrict__ distp) {
    __shared__ float As[BK][TILE];
    __shared__ float Bs[BK][TILE];
    const int tid = threadIdx.x;
    const int tx = tid & 15;
    const int ty = tid >> 4;
    const int row0 = blockIdx.y * TILE;
    const int col0 = blockIdx.x * TILE;

    const int r = tid >> 2;            // 0..63 (tile row this thread stages)
    const int kq = tid & 3;            // float4 slot along k
    const int brow = sj[col0 + r];     // permuted B-side source row (fixed)

    float acc[4][4] = {};

    for (int k0 = 0; k0 < DD; k0 += BK) {
        {
            const float4 a = *reinterpret_cast<const float4*>(
                &cf[(size_t)(row0 + r) * DD + k0 + kq * 4]);
            As[kq * 4 + 0][r] = a.x; As[kq * 4 + 1][r] = a.y;
            As[kq * 4 + 2][r] = a.z; As[kq * 4 + 3][r] = a.w;
            const float4 bvec = *reinterpret_cast<const float4*>(
                &cf[(size_t)brow * DD + k0 + kq * 4]);
            Bs[kq * 4 + 0][r] = bvec.x; Bs[kq * 4 + 1][r] = bvec.y;
            Bs[kq * 4 + 2][r] = bvec.z; Bs[kq * 4 + 3][r] = bvec.w;
        }
        __syncthreads();
        #pragma unroll
        for (int kk = 0; kk < BK; ++kk) {
            const float4 a4 = *reinterpret_cast<const float4*>(&As[kk][ty * 4]);
            const float4 b4 = *reinterpret_cast<const float4*>(&Bs[kk][tx * 4]);
            const float ar[4] = {a4.x, a4.y, a4.z, a4.w};
            const float br[4] = {b4.x, b4.y, b4.z, b4.w};
            #pragma unroll
            for (int rr = 0; rr < 4; ++rr)
                #pragma unroll
                for (int cc = 0; cc < 4; ++cc)
                    acc[rr][cc] = fmaf(ar[rr], br[cc], acc[rr][cc]);
        }
        __syncthreads();
    }

    float sjv[4];
    #pragma unroll
    for (int cc = 0; cc < 4; ++cc) sjv[cc] = sq[sj[col0 + tx * 4 + cc]];
    #pragma unroll
    for (int rr = 0; rr < 4; ++rr) {
        const int gi = row0 + ty * 4 + rr;
        const float si = sq[gi];
        float4 o;
        float* op = &o.x;
        #pragma unroll
        for (int cc = 0; cc < 4; ++cc) {
            const float d2 = si + sjv[cc] - 2.f * acc[rr][cc];
            op[cc] = (d2 > 0.f) ? sqrtf(d2) : 0.f;
        }
        *reinterpret_cast<float4*>(&distp[(size_t)gi * NN + col0 + tx * 4]) = o;
    }
}

// ---------------- kernel 3: per-row scans + window lookup ----------------
__device__ __forceinline__ void lse_combine(float& m, float& s, float nm, float ns) {
    if (nm == NEGINF) return;
    if (m == NEGINF) { m = nm; s = ns; return; }
    if (nm <= m) { s += ns * expf(nm - m); }
    else         { s = ns + s * expf(m - nm); m = nm; }
}

__device__ __forceinline__ float lse_pair(float a, float b) {
    if (a == NEGINF) return b;
    if (b == NEGINF) return a;
    const float mx = fmaxf(a, b);
    const float mn = fminf(a, b);
    return mx + log1pf(expf(mn - mx));
}

__global__ __launch_bounds__(256) void row_kernel(const float* __restrict__ distp,
                                                  const float* __restrict__ labels,
                                                  const float* __restrict__ slab,
                                                  const int* __restrict__ inv,
                                                  double* __restrict__ rowval) {
    __shared__ float key[NN];
    __shared__ float val[NN];
    __shared__ float Plog[NN + 1];
    __shared__ float Slog[NN + 1];
    __shared__ float ctM[NT];
    __shared__ float ctS[NT];
    __shared__ double red[NT];

    const int i = blockIdx.x;
    const int t = threadIdx.x;
    const int pos_i = inv[i];
    const float x = labels[i & (BB - 1)];
    const float negInvT = -1.0f / 0.07f;
    const float* drow = &distp[(size_t)i * NN];

    // ---- load row (columns already label-sorted), build key/val ----
    double dsum = 0.0;
    #pragma unroll
    for (int e = 0; e < 2; ++e) {
        const int p4 = t + e * NT;
        const int p = p4 * 4;
        const float4 d4 = reinterpret_cast<const float4*>(drow)[p4];
        const float4 l4 = reinterpret_cast<const float4*>(slab)[p4];
        const float dv[4] = {d4.x, d4.y, d4.z, d4.w};
        const float lv[4] = {l4.x, l4.y, l4.z, l4.w};
        #pragma unroll
        for (int c = 0; c < 4; ++c) {
            const int pc = p + c;
            key[pc] = fabsf(lv[c] - x);
            if (pc == pos_i) {
                val[pc] = NEGINF;            // diag excluded from LSE and dsum
            } else {
                val[pc] = dv[c] * negInvT;
                dsum += (double)dv[c];
            }
        }
    }
    __syncthreads();

    const int cb = t * 8;

    // ---- prefix LSE scan: Plog[p] = log sum_{q<p} exp(val[q]) ----
    float lm[8], ls[8];
    {
        float m = NEGINF, s = 0.f;
        #pragma unroll
        for (int jj = 0; jj < 8; ++jj) {
            lm[jj] = m; ls[jj] = s;          // exclusive state
            const float vv = val[cb + jj];
            if (vv != NEGINF) {
                if (m == NEGINF) { m = vv; s = 1.f; }
                else if (vv <= m) { s += expf(vv - m); }
                else { s = s * expf(m - vv) + 1.f; m = vv; }
            }
        }
        ctM[t] = m; ctS[t] = s;
    }
    __syncthreads();
    for (int st = 1; st < NT; st <<= 1) {
        float nm = NEGINF, ns = 0.f;
        if (t >= st) { nm = ctM[t - st]; ns = ctS[t - st]; }
        __syncthreads();
        float m = ctM[t], s = ctS[t];
        lse_combine(m, s, nm, ns);
        ctM[t] = m; ctS[t] = s;
        __syncthreads();
    }
    {
        float pm = NEGINF, ps = 0.f;
        if (t > 0) { pm = ctM[t - 1]; ps = ctS[t - 1]; }
        #pragma unroll
        for (int jj = 0; jj < 8; ++jj) {
            float m = lm[jj], s = ls[jj];
            lse_combine(m, s, pm, ps);
            Plog[cb + jj] = (m == NEGINF) ? NEGINF : (m + logf(s));
        }
        if (t == NT - 1) {
            const float m = ctM[NT - 1], s = ctS[NT - 1];
            Plog[NN] = (m == NEGINF) ? NEGINF : (m + logf(s));
        }
    }
    __syncthreads();

    // ---- suffix LSE scan: Slog[p] = log sum_{q>=p} exp(val[q]) ----
    {
        float m = NEGINF, s = 0.f;
        #pragma unroll
        for (int jj = 7; jj >= 0; --jj) {
            const float vv = val[cb + jj];
            if (vv != NEGINF) {
                if (m == NEGINF) { m = vv; s = 1.f; }
                else if (vv <= m) { s += expf(vv - m); }
                else { s = s * expf(m - vv) + 1.f; m = vv; }
            }
            lm[jj] = m; ls[jj] = s;          // inclusive state
        }
        ctM[t] = m; ctS[t] = s;
    }
    __syncthreads();
    for (int st = 1; st < NT; st <<= 1) {
        float nm = NEGINF, ns = 0.f;
        if (t + st < NT) { nm = ctM[t + st]; ns = ctS[t + st]; }
        __syncthreads();
        float m = ctM[t], s = ctS[t];
        lse_combine(m, s, nm, ns);
        ctM[t] = m; ctS[t] = s;
        __syncthreads();
    }
    {
        float sm = NEGINF, ss = 0.f;
        if (t + 1 < NT) { sm = ctM[t + 1]; ss = ctS[t + 1]; }
        #pragma unroll
        for (int jj = 0; jj < 8; ++jj) {
            float m = lm[jj], s = ls[jj];
            lse_combine(m, s, sm, ss);
            Slog[cb + jj] = (m == NEGINF) ? NEGINF : (m + logf(s));
        }
        if (t == 0) Slog[NN] = NEGINF;
    }
    __syncthreads();

    // ---- per element: window [L,R) = {key < d}, negative = P[L] (+) S[R] ----
    double lnsum = 0.0;
    #pragma unroll
    for (int jj = 0; jj < 8; ++jj) {
        const int p = cb + jj;
        if (p == pos_i) continue;
        const float d = key[p];
        // L: first index in [0,pos_i] with key < d (left segment non-increasing)
        int lo = 0, hi = pos_i;
        while (lo < hi) {
            const int mid = (lo + hi) >> 1;
            if (key[mid] < d) hi = mid; else lo = mid + 1;
        }
        const int L = lo;
        // R: first index in [pos_i,NN] with key >= d (right segment non-decreasing)
        lo = pos_i; hi = NN;
        while (lo < hi) {
            const int mid = (lo + hi) >> 1;
            if (key[mid] >= d) hi = mid; else lo = mid + 1;
        }
        const int R = lo;
        lnsum += (double)lse_pair(Plog[L], Slog[R]);
    }

    // ---- reductions ----
    red[t] = dsum;
    __syncthreads();
    for (int ofs = NT / 2; ofs > 0; ofs >>= 1) {
        if (t < ofs) red[t] += red[t + ofs];
        __syncthreads();
    }
    const double total_d = red[0];
    __syncthreads();
    red[t] = lnsum;
    __syncthreads();
    for (int ofs = NT / 2; ofs > 0; ofs >>= 1) {
        if (t < ofs) red[t] += red[t + ofs];
        __syncthreads();
    }
    if (t == 0) {
        rowval[i] = (-total_d / 0.07) - red[0];
    }
}

// ---------------- kernel 4: final mean ----------------
__global__ __launch_bounds__(256) void finalize_kernel(const double* __restrict__ rowval,
                                                       float* __restrict__ out) {
    __shared__ double red[NT];
    const int t = threadIdx.x;
    double s = 0.0;
    for (int j = t; j < NN; j += NT) s += rowval[j];
    red[t] = s;
    __syncthreads();
    for (int ofs = NT / 2; ofs > 0; ofs >>= 1) {
        if (t < ofs) red[t] += red[t + ofs];
        __syncthreads();
    }
    if (t == 0) {
        out[0] = (float)(-red[0] / ((double)NN * (double)(NN - 1)));
    }
}

extern "C" void kernel_launch(void* const* d_in, const int* in_sizes, int n_in,
                              void* d_out, int out_size, void* d_ws, size_t ws_size,
                              hipStream_t stream) {
    const float* features = (const float*)d_in[0];  // [1024, 2, 512] fp32
    const float* labels   = (const float*)d_in[1];  // [1024] fp32
    float* out = (float*)d_out;

    char* ws = (char*)d_ws;
    size_t off = 0;
    float* cf     = (float*)(ws + off); off += (size_t)NN * DD * sizeof(float);   // 4 MB
    float* sq     = (float*)(ws + off); off += NN * sizeof(float);                // 8 KB
    float* slab   = (float*)(ws + off); off += NN * sizeof(float);                // 8 KB
    int*   sj     = (int*)  (ws + off); off += NN * sizeof(int);                  // 8 KB
    int*   inv    = (int*)  (ws + off); off += NN * sizeof(int);                  // 8 KB
    float* distp  = (float*)(ws + off); off += (size_t)NN * NN * sizeof(float);   // 16 MB
    double* rowval = (double*)(ws + off);                                         // 16 KB

    sort_labels_kernel<<<1, NT, 0, stream>>>(labels, slab, sj, inv);
    prep_kernel<<<NN, NT, 0, stream>>>(features, cf, sq);
    dim3 ggrid(NN / TILE, NN / TILE);
    gemm_dist_kernel<<<ggrid, NT, 0, stream>>>(cf, sq, sj, distp);
    row_kernel<<<NN, NT, 0, stream>>>(distp, labels, slab, inv, rowval);
    finalize_kernel<<<1, NT, 0, stream>>>(rowval, out);
}

// Round 3
// 226.831 us; speedup vs baseline: 1.5716x; 1.0171x over previous
//
#include <hip/hip_runtime.h>
#include <math.h>

// SupCR loss, MI355X. Round 3:
//  - GEMM: 128x128 tile, 8x8 acc/thread, double-buffered LDS (1 barrier/K-step),
//    reads `features` directly (cf copy eliminated).
//  - row_kernel: wave-shuffle LSE scans (5 barriers total, was ~36).
// Math identical to round 2: global label sort once; per-row valley keys ->
// window [L,R) via 2 binary searches; negative = prefixLSE[L] (+) suffixLSE[R].

#define NN 2048      // N = B*V
#define BB 1024      // B
#define DD 512       // D
#define NT 256       // threads per block
#define NEGINF (-INFINITY)

// row i of the virtual cf matrix lives at F + ((i%B)*2 + i/B)*D
__device__ __forceinline__ const float* cf_row(const float* F, int i) {
    return F + ((size_t)(i & (BB - 1)) * 2 + (size_t)(i >> 10)) * DD;
}

// ---------------- kernel 0: sort labels once ----------------
__global__ __launch_bounds__(256) void sort_labels_kernel(const float* __restrict__ labels,
                                                          float* __restrict__ slab,
                                                          int* __restrict__ sj,
                                                          int* __restrict__ inv) {
    __shared__ float kk[BB];
    __shared__ int   id[BB];
    const int t = threadIdx.x;
    #pragma unroll
    for (int e = 0; e < 4; ++e) { const int p = t + e * NT; kk[p] = labels[p]; id[p] = p; }
    for (int k = 2; k <= BB; k <<= 1) {
        for (int j = k >> 1; j > 0; j >>= 1) {
            __syncthreads();
            #pragma unroll
            for (int e = 0; e < 4; ++e) {
                const int idx = t + e * NT;
                const int ixj = idx ^ j;
                if (ixj > idx) {
                    const float k1 = kk[idx], k2 = kk[ixj];
                    const bool up = ((idx & k) == 0);
                    if (up ? (k1 > k2) : (k1 < k2)) {
                        kk[idx] = k2; kk[ixj] = k1;
                        const int i1 = id[idx]; id[idx] = id[ixj]; id[ixj] = i1;
                    }
                }
            }
        }
    }
    __syncthreads();
    #pragma unroll
    for (int e = 0; e < 4; ++e) {
        const int p = t + e * NT;
        const float lv = kk[p];
        const int b = id[p];
        slab[2 * p] = lv; slab[2 * p + 1] = lv;
        sj[2 * p] = b;    sj[2 * p + 1] = b + BB;
        inv[b] = 2 * p;   inv[b + BB] = 2 * p + 1;
    }
}

// ---------------- kernel 1: squared norms (one wave per row) ----------------
__global__ __launch_bounds__(256) void sqnorm_kernel(const float* __restrict__ F,
                                                     float* __restrict__ sq) {
    const int t = threadIdx.x;
    const int lane = t & 63;
    const int w = t >> 6;
    const int i = blockIdx.x * 4 + w;
    const float* src = cf_row(F, i);
    const float4 v0 = reinterpret_cast<const float4*>(src)[lane];
    const float4 v1 = reinterpret_cast<const float4*>(src)[lane + 64];
    float ss = v0.x * v0.x + v0.y * v0.y + v0.z * v0.z + v0.w * v0.w
             + v1.x * v1.x + v1.y * v1.y + v1.z * v1.z + v1.w * v1.w;
    #pragma unroll
    for (int st = 32; st > 0; st >>= 1) ss += __shfl_down(ss, st);
    if (lane == 0) sq[i] = ss;
}

// ---------------- kernel 2: dist, 128x128 tile, double-buffered ----------------
#define GT 128
#define GBK 16
__global__ __launch_bounds__(256) void gemm_dist_kernel(const float* __restrict__ F,
                                                        const float* __restrict__ sq,
                                                        const int* __restrict__ sj,
                                                        float* __restrict__ distp) {
    __shared__ float As[2][GBK][GT];
    __shared__ float Bs[2][GBK][GT];
    const int tid = threadIdx.x;
    const int tx = tid & 15;
    const int ty = tid >> 4;
    const int row0 = blockIdx.y * GT;
    const int col0 = blockIdx.x * GT;

    // staging: lane handles float4 slots q0,q0+1 of tile-row lr
    const int lr = tid >> 1;
    const int q0 = (tid & 1) * 2;
    const float* aptr = cf_row(F, row0 + lr) + q0 * 4;
    const float* bptr = cf_row(F, sj[col0 + lr]) + q0 * 4;

    float4 ra0 = reinterpret_cast<const float4*>(aptr)[0];
    float4 ra1 = reinterpret_cast<const float4*>(aptr)[1];
    float4 rb0 = reinterpret_cast<const float4*>(bptr)[0];
    float4 rb1 = reinterpret_cast<const float4*>(bptr)[1];
    {
        const int kb = q0 * 4;
        As[0][kb + 0][lr] = ra0.x; As[0][kb + 1][lr] = ra0.y;
        As[0][kb + 2][lr] = ra0.z; As[0][kb + 3][lr] = ra0.w;
        As[0][kb + 4][lr] = ra1.x; As[0][kb + 5][lr] = ra1.y;
        As[0][kb + 6][lr] = ra1.z; As[0][kb + 7][lr] = ra1.w;
        Bs[0][kb + 0][lr] = rb0.x; Bs[0][kb + 1][lr] = rb0.y;
        Bs[0][kb + 2][lr] = rb0.z; Bs[0][kb + 3][lr] = rb0.w;
        Bs[0][kb + 4][lr] = rb1.x; Bs[0][kb + 5][lr] = rb1.y;
        Bs[0][kb + 6][lr] = rb1.z; Bs[0][kb + 7][lr] = rb1.w;
    }
    __syncthreads();

    float acc[8][8] = {};
    const int KT = DD / GBK;   // 32
    for (int kt = 0; kt < KT; ++kt) {
        const int cur = kt & 1;
        if (kt + 1 < KT) {
            const float* ap = aptr + (kt + 1) * GBK;
            const float* bp = bptr + (kt + 1) * GBK;
            ra0 = reinterpret_cast<const float4*>(ap)[0];
            ra1 = reinterpret_cast<const float4*>(ap)[1];
            rb0 = reinterpret_cast<const float4*>(bp)[0];
            rb1 = reinterpret_cast<const float4*>(bp)[1];
        }
        #pragma unroll
        for (int kk = 0; kk < GBK; ++kk) {
            const float4 a0 = *reinterpret_cast<const float4*>(&As[cur][kk][ty * 4]);
            const float4 a1 = *reinterpret_cast<const float4*>(&As[cur][kk][64 + ty * 4]);
            const float4 b0 = *reinterpret_cast<const float4*>(&Bs[cur][kk][tx * 4]);
            const float4 b1 = *reinterpret_cast<const float4*>(&Bs[cur][kk][64 + tx * 4]);
            const float ar[8] = {a0.x, a0.y, a0.z, a0.w, a1.x, a1.y, a1.z, a1.w};
            const float br[8] = {b0.x, b0.y, b0.z, b0.w, b1.x, b1.y, b1.z, b1.w};
            #pragma unroll
            for (int r = 0; r < 8; ++r)
                #pragma unroll
                for (int c = 0; c < 8; ++c)
                    acc[r][c] = fmaf(ar[r], br[c], acc[r][c]);
        }
        if (kt + 1 < KT) {
            const int nb = (kt + 1) & 1;
            const int kb = q0 * 4;
            As[nb][kb + 0][lr] = ra0.x; As[nb][kb + 1][lr] = ra0.y;
            As[nb][kb + 2][lr] = ra0.z; As[nb][kb + 3][lr] = ra0.w;
            As[nb][kb + 4][lr] = ra1.x; As[nb][kb + 5][lr] = ra1.y;
            As[nb][kb + 6][lr] = ra1.z; As[nb][kb + 7][lr] = ra1.w;
            Bs[nb][kb + 0][lr] = rb0.x; Bs[nb][kb + 1][lr] = rb0.y;
            Bs[nb][kb + 2][lr] = rb0.z; Bs[nb][kb + 3][lr] = rb0.w;
            Bs[nb][kb + 4][lr] = rb1.x; Bs[nb][kb + 5][lr] = rb1.y;
            Bs[nb][kb + 6][lr] = rb1.z; Bs[nb][kb + 7][lr] = rb1.w;
        }
        __syncthreads();
    }

    // epilogue
    float si[8], sjv[8];
    #pragma unroll
    for (int r = 0; r < 8; ++r) {
        const int rIdx = ty * 4 + (r & 3) + (r >> 2) * 64;
        si[r] = sq[row0 + rIdx];
    }
    #pragma unroll
    for (int c = 0; c < 8; ++c) {
        const int cIdx = tx * 4 + (c & 3) + (c >> 2) * 64;
        sjv[c] = sq[sj[col0 + cIdx]];
    }
    #pragma unroll
    for (int r = 0; r < 8; ++r) {
        const int gr = row0 + ty * 4 + (r & 3) + (r >> 2) * 64;
        const size_t base = (size_t)gr * NN + col0;
        float4 o0, o1;
        float* p0 = &o0.x;
        float* p1 = &o1.x;
        #pragma unroll
        for (int c = 0; c < 4; ++c) {
            const float d2 = si[r] + sjv[c] - 2.f * acc[r][c];
            p0[c] = (d2 > 0.f) ? sqrtf(d2) : 0.f;
        }
        #pragma unroll
        for (int c = 0; c < 4; ++c) {
            const float d2 = si[r] + sjv[c + 4] - 2.f * acc[r][c + 4];
            p1[c] = (d2 > 0.f) ? sqrtf(d2) : 0.f;
        }
        *reinterpret_cast<float4*>(&distp[base + tx * 4]) = o0;
        *reinterpret_cast<float4*>(&distp[base + 64 + tx * 4]) = o1;
    }
}

// ---------------- kernel 3: per-row scans + window lookup ----------------
__device__ __forceinline__ void lse_combine(float& m, float& s, float nm, float ns) {
    if (nm == NEGINF) return;
    if (m == NEGINF) { m = nm; s = ns; return; }
    if (nm <= m) { s += ns * expf(nm - m); }
    else         { s = ns + s * expf(m - nm); m = nm; }
}

__device__ __forceinline__ float lse_fin(float m, float s) {
    return (m == NEGINF) ? NEGINF : (m + logf(s));
}

__device__ __forceinline__ float lse_pair(float a, float b) {
    if (a == NEGINF) return b;
    if (b == NEGINF) return a;
    const float mx = fmaxf(a, b);
    const float mn = fminf(a, b);
    return mx + log1pf(expf(mn - mx));
}

__global__ __launch_bounds__(256) void row_kernel(const float* __restrict__ distp,
                                                  const float* __restrict__ labels,
                                                  const float* __restrict__ slab,
                                                  const int* __restrict__ inv,
                                                  double* __restrict__ rowval) {
    __shared__ float key[NN];
    __shared__ float val[NN];
    __shared__ float Plog[NN + 1];
    __shared__ float Slog[NN + 1];
    __shared__ float wM[4], wS[4], wM2[4], wS2[4];
    __shared__ double wD[4], wL[4];

    const int i = blockIdx.x;
    const int t = threadIdx.x;
    const int lane = t & 63;
    const int w = t >> 6;
    const int pos_i = inv[i];
    const float x = labels[i & (BB - 1)];
    const float negInvT = -1.0f / 0.07f;
    const float* drow = &distp[(size_t)i * NN];

    // ---- load row (label-sorted columns), build key/val ----
    double dsum = 0.0;
    #pragma unroll
    for (int e = 0; e < 2; ++e) {
        const int p4 = t + e * NT;
        const int p = p4 * 4;
        const float4 d4 = reinterpret_cast<const float4*>(drow)[p4];
        const float4 l4 = reinterpret_cast<const float4*>(slab)[p4];
        const float dv[4] = {d4.x, d4.y, d4.z, d4.w};
        const float lv[4] = {l4.x, l4.y, l4.z, l4.w};
        #pragma unroll
        for (int c = 0; c < 4; ++c) {
            const int pc = p + c;
            key[pc] = fabsf(lv[c] - x);
            if (pc == pos_i) {
                val[pc] = NEGINF;
            } else {
                val[pc] = dv[c] * negInvT;
                dsum += (double)dv[c];
            }
        }
    }
    __syncthreads();   // B1: key/val ready

    const int cb = t * 8;
    float em[8], es[8];

    // ---- prefix LSE: chunk-local exclusive states + chunk total ----
    {
        float m = NEGINF, s = 0.f;
        #pragma unroll
        for (int jj = 0; jj < 8; ++jj) {
            em[jj] = m; es[jj] = s;
            const float vv = val[cb + jj];
            if (vv != NEGINF) {
                if (m == NEGINF) { m = vv; s = 1.f; }
                else if (vv <= m) { s += expf(vv - m); }
                else { s = s * expf(m - vv) + 1.f; m = vv; }
            }
        }
        // wave inclusive scan of chunk totals
        float im = m, is = s;
        #pragma unroll
        for (int st = 1; st < 64; st <<= 1) {
            const float nm = __shfl_up(im, st);
            const float ns = __shfl_up(is, st);
            if (lane >= st) lse_combine(im, is, nm, ns);
        }
        float xm = __shfl_up(im, 1);
        float xs = __shfl_up(is, 1);
        if (lane == 0) { xm = NEGINF; xs = 0.f; }
        if (lane == 63) { wM[w] = im; wS[w] = is; }
        __syncthreads();   // B2: wave totals ready
        #pragma unroll
        for (int ww = 0; ww < 3; ++ww)
            if (ww < w) lse_combine(xm, xs, wM[ww], wS[ww]);
        #pragma unroll
        for (int jj = 0; jj < 8; ++jj) {
            float m2 = em[jj], s2 = es[jj];
            lse_combine(m2, s2, xm, xs);
            Plog[cb + jj] = lse_fin(m2, s2);
        }
        if (t == 0) {
            float m2 = NEGINF, s2 = 0.f;
            #pragma unroll
            for (int ww = 0; ww < 4; ++ww) lse_combine(m2, s2, wM[ww], wS[ww]);
            Plog[NN] = lse_fin(m2, s2);
        }
    }

    // ---- suffix LSE: chunk-local inclusive states ----
    {
        float m = NEGINF, s = 0.f;
        #pragma unroll
        for (int jj = 7; jj >= 0; --jj) {
            const float vv = val[cb + jj];
            if (vv != NEGINF) {
                if (m == NEGINF) { m = vv; s = 1.f; }
                else if (vv <= m) { s += expf(vv - m); }
                else { s = s * expf(m - vv) + 1.f; m = vv; }
            }
            em[jj] = m; es[jj] = s;
        }
        float im = m, is = s;
        #pragma unroll
        for (int st = 1; st < 64; st <<= 1) {
            const float nm = __shfl_down(im, st);
            const float ns = __shfl_down(is, st);
            if (lane + st < 64) lse_combine(im, is, nm, ns);
        }
        float xm = __shfl_down(im, 1);
        float xs = __shfl_down(is, 1);
        if (lane == 63) { xm = NEGINF; xs = 0.f; }
        if (lane == 0) { wM2[w] = im; wS2[w] = is; }
        __syncthreads();   // B3: (also orders Plog writes) wave totals ready
        #pragma unroll
        for (int ww = 1; ww < 4; ++ww)
            if (ww > w) lse_combine(xm, xs, wM2[ww], wS2[ww]);
        #pragma unroll
        for (int jj = 0; jj < 8; ++jj) {
            float m2 = em[jj], s2 = es[jj];
            lse_combine(m2, s2, xm, xs);
            Slog[cb + jj] = lse_fin(m2, s2);
        }
        if (t == 0) Slog[NN] = NEGINF;
    }
    __syncthreads();   // B4: Plog/Slog ready

    // ---- per element: [L,R) = {key < d}; negative = P[L] (+) S[R] ----
    double lnsum = 0.0;
    #pragma unroll
    for (int jj = 0; jj < 8; ++jj) {
        const int p = cb + jj;
        if (p == pos_i) continue;
        const float d = key[p];
        int lo = 0, hi = pos_i;                 // left segment: non-increasing
        while (lo < hi) {
            const int mid = (lo + hi) >> 1;
            if (key[mid] < d) hi = mid; else lo = mid + 1;
        }
        const int L = lo;
        lo = pos_i; hi = NN;                    // right segment: non-decreasing
        while (lo < hi) {
            const int mid = (lo + hi) >> 1;
            if (key[mid] >= d) hi = mid; else lo = mid + 1;
        }
        const int R = lo;
        lnsum += (double)lse_pair(Plog[L], Slog[R]);
    }

    // ---- wave reductions ----
    #pragma unroll
    for (int st = 32; st > 0; st >>= 1) {
        dsum  += __shfl_down(dsum, st);
        lnsum += __shfl_down(lnsum, st);
    }
    if (lane == 0) { wD[w] = dsum; wL[w] = lnsum; }
    __syncthreads();   // B5
    if (t == 0) {
        const double td = wD[0] + wD[1] + wD[2] + wD[3];
        const double tl = wL[0] + wL[1] + wL[2] + wL[3];
        rowval[i] = (-td / 0.07) - tl;
    }
}

// ---------------- kernel 4: final mean ----------------
__global__ __launch_bounds__(256) void finalize_kernel(const double* __restrict__ rowval,
                                                       float* __restrict__ out) {
    __shared__ double red[NT];
    const int t = threadIdx.x;
    double s = 0.0;
    for (int j = t; j < NN; j += NT) s += rowval[j];
    red[t] = s;
    __syncthreads();
    for (int ofs = NT / 2; ofs > 0; ofs >>= 1) {
        if (t < ofs) red[t] += red[t + ofs];
        __syncthreads();
    }
    if (t == 0) {
        out[0] = (float)(-red[0] / ((double)NN * (double)(NN - 1)));
    }
}

extern "C" void kernel_launch(void* const* d_in, const int* in_sizes, int n_in,
                              void* d_out, int out_size, void* d_ws, size_t ws_size,
                              hipStream_t stream) {
    const float* features = (const float*)d_in[0];  // [1024, 2, 512] fp32
    const float* labels   = (const float*)d_in[1];  // [1024] fp32
    float* out = (float*)d_out;

    char* ws = (char*)d_ws;
    size_t off = 0;
    float* sq     = (float*)(ws + off); off += NN * sizeof(float);
    float* slab   = (float*)(ws + off); off += NN * sizeof(float);
    int*   sj     = (int*)  (ws + off); off += NN * sizeof(int);
    int*   inv    = (int*)  (ws + off); off += NN * sizeof(int);
    float* distp  = (float*)(ws + off); off += (size_t)NN * NN * sizeof(float);
    double* rowval = (double*)(ws + off);

    sort_labels_kernel<<<1, NT, 0, stream>>>(labels, slab, sj, inv);
    sqnorm_kernel<<<NN / 4, NT, 0, stream>>>(features, sq);
    dim3 ggrid(NN / GT, NN / GT);
    gemm_dist_kernel<<<ggrid, NT, 0, stream>>>(features, sq, sj, distp);
    row_kernel<<<NN, NT, 0, stream>>>(distp, labels, slab, inv, rowval);
    finalize_kernel<<<1, NT, 0, stream>>>(rowval, out);
}

// Round 4
// 188.644 us; speedup vs baseline: 1.8897x; 1.2024x over previous
//
#include <hip/hip_runtime.h>
#include <math.h>

// SupCR loss, MI355X. Round 4: GEMM on the matrix cores.
// fp32 dot products via 3-term bf16 split (hi+lo, RNE):
//   dot ~= hi.hi + hi.lo + lo.hi   (error ~512*2^-18 ~ 0.002 abs on d2~1024)
// mfma_f32_16x16x32_bf16, tile 128x64, BK=32, LDS layout [q][row][8] so each
// fragment load is one aligned ds_read_b128. Diagonal dist error is harmless:
// diag excluded from dsum and LSE in row_kernel.
// Rest of pipeline unchanged from round 3 (global label sort -> valley window
// binary search -> prefix/suffix LSE with wave-shuffle scans).

#define NN 2048      // N = B*V
#define BB 1024      // B
#define DD 512       // D
#define NT 256       // threads per block
#define NEGINF (-INFINITY)

typedef short s16x8 __attribute__((ext_vector_type(8)));
typedef float f32x4 __attribute__((ext_vector_type(4)));

// row i of the virtual cf matrix lives at F + ((i%B)*2 + i/B)*D
__device__ __forceinline__ const float* cf_row(const float* F, int i) {
    return F + ((size_t)(i & (BB - 1)) * 2 + (size_t)(i >> 10)) * DD;
}

__device__ __forceinline__ unsigned bf_rne(float x) {
    const unsigned u = __float_as_uint(x);
    return (u + 0x7FFFu + ((u >> 16) & 1u)) >> 16;
}
__device__ __forceinline__ float bf_val(unsigned h) {
    return __uint_as_float(h << 16);
}

// ---------------- kernel 0: sort labels once ----------------
__global__ __launch_bounds__(256) void sort_labels_kernel(const float* __restrict__ labels,
                                                          float* __restrict__ slab,
                                                          int* __restrict__ sj,
                                                          int* __restrict__ inv) {
    __shared__ float kk[BB];
    __shared__ int   id[BB];
    const int t = threadIdx.x;
    #pragma unroll
    for (int e = 0; e < 4; ++e) { const int p = t + e * NT; kk[p] = labels[p]; id[p] = p; }
    for (int k = 2; k <= BB; k <<= 1) {
        for (int j = k >> 1; j > 0; j >>= 1) {
            __syncthreads();
            #pragma unroll
            for (int e = 0; e < 4; ++e) {
                const int idx = t + e * NT;
                const int ixj = idx ^ j;
                if (ixj > idx) {
                    const float k1 = kk[idx], k2 = kk[ixj];
                    const bool up = ((idx & k) == 0);
                    if (up ? (k1 > k2) : (k1 < k2)) {
                        kk[idx] = k2; kk[ixj] = k1;
                        const int i1 = id[idx]; id[idx] = id[ixj]; id[ixj] = i1;
                    }
                }
            }
        }
    }
    __syncthreads();
    #pragma unroll
    for (int e = 0; e < 4; ++e) {
        const int p = t + e * NT;
        const float lv = kk[p];
        const int b = id[p];
        slab[2 * p] = lv; slab[2 * p + 1] = lv;
        sj[2 * p] = b;    sj[2 * p + 1] = b + BB;
        inv[b] = 2 * p;   inv[b + BB] = 2 * p + 1;
    }
}

// ---------------- kernel 1: bf16 hi/lo split + squared norms ----------------
__global__ __launch_bounds__(256) void prep_split_kernel(const float* __restrict__ F,
                                                         ushort* __restrict__ Ahi,
                                                         ushort* __restrict__ Alo,
                                                         float* __restrict__ sq) {
    const int t = threadIdx.x;
    const int lane = t & 63;
    const int w = t >> 6;
    const int i = blockIdx.x * 4 + w;
    const float* src = cf_row(F, i);
    const float4 v0 = reinterpret_cast<const float4*>(src)[lane];
    const float4 v1 = reinterpret_cast<const float4*>(src)[lane + 64];
    float ss = v0.x * v0.x + v0.y * v0.y + v0.z * v0.z + v0.w * v0.w
             + v1.x * v1.x + v1.y * v1.y + v1.z * v1.z + v1.w * v1.w;
    #pragma unroll
    for (int st = 32; st > 0; st >>= 1) ss += __shfl_down(ss, st);
    if (lane == 0) sq[i] = ss;

    const float a[8] = {v0.x, v0.y, v0.z, v0.w, v1.x, v1.y, v1.z, v1.w};
    ushort h[8], l[8];
    #pragma unroll
    for (int e = 0; e < 8; ++e) {
        const unsigned hb = bf_rne(a[e]);
        h[e] = (ushort)hb;
        l[e] = (ushort)bf_rne(a[e] - bf_val(hb));
    }
    const size_t base = (size_t)i * DD;
    *reinterpret_cast<ushort4*>(&Ahi[base + lane * 4])       = make_ushort4(h[0], h[1], h[2], h[3]);
    *reinterpret_cast<ushort4*>(&Ahi[base + 256 + lane * 4]) = make_ushort4(h[4], h[5], h[6], h[7]);
    *reinterpret_cast<ushort4*>(&Alo[base + lane * 4])       = make_ushort4(l[0], l[1], l[2], l[3]);
    *reinterpret_cast<ushort4*>(&Alo[base + 256 + lane * 4]) = make_ushort4(l[4], l[5], l[6], l[7]);
}

// ---------------- kernel 2: MFMA dist, 128x64 tile ----------------
#define TM 128
#define TN 64
#define TK 32
__global__ __launch_bounds__(256) void gemm_dist_kernel(const ushort* __restrict__ Ahi,
                                                        const ushort* __restrict__ Alo,
                                                        const float* __restrict__ sq,
                                                        const int* __restrict__ sj,
                                                        float* __restrict__ distp) {
    // [q][row][8]: fragment (lane l: row=l&15 band, k=q*8..q*8+7) = 1 ds_read_b128
    __shared__ ushort Ah[4][TM][8];
    __shared__ ushort Al[4][TM][8];
    __shared__ ushort Bh[4][TN][8];
    __shared__ ushort Bl[4][TN][8];
    __shared__ int   sjc[TN];
    __shared__ float sqA[TM];
    __shared__ float sqB[TN];

    const int t = threadIdx.x;
    const int lane = t & 63;
    const int w = t >> 6;          // 4 waves; wave w owns rows w*32..w*32+31
    const int row0 = blockIdx.y * TM;
    const int col0 = blockIdx.x * TN;

    if (t < TN) {
        const int s = sj[col0 + t];
        sjc[t] = s;
        sqB[t] = sq[s];
    } else if (t < TN + TM) {
        sqA[t - TN] = sq[row0 + (t - TN)];
    }

    f32x4 acc[2][4] = {};
    const int m = lane & 15;
    const int q = lane >> 4;

    for (int kt = 0; kt < DD / TK; ++kt) {
        __syncthreads();   // prev compute done / sjc ready (first iter)
        // stage A: 512 16B-chunks hi + lo
        for (int c = t; c < TM * 4; c += NT) {
            const int row = c >> 2, cq = c & 3;
            const size_t g = (size_t)(row0 + row) * DD + kt * TK + cq * 8;
            *reinterpret_cast<int4*>(&Ah[cq][row][0]) = *reinterpret_cast<const int4*>(&Ahi[g]);
            *reinterpret_cast<int4*>(&Al[cq][row][0]) = *reinterpret_cast<const int4*>(&Alo[g]);
        }
        // stage B: 256 chunks hi + lo (row-permuted source)
        for (int c = t; c < TN * 4; c += NT) {
            const int row = c >> 2, cq = c & 3;
            const size_t g = (size_t)sjc[row] * DD + kt * TK + cq * 8;
            *reinterpret_cast<int4*>(&Bh[cq][row][0]) = *reinterpret_cast<const int4*>(&Ahi[g]);
            *reinterpret_cast<int4*>(&Bl[cq][row][0]) = *reinterpret_cast<const int4*>(&Alo[g]);
        }
        __syncthreads();

        s16x8 fah[2], fal[2], fbh[4], fbl[4];
        #pragma unroll
        for (int mt = 0; mt < 2; ++mt) {
            fah[mt] = *reinterpret_cast<const s16x8*>(&Ah[q][w * 32 + mt * 16 + m][0]);
            fal[mt] = *reinterpret_cast<const s16x8*>(&Al[q][w * 32 + mt * 16 + m][0]);
        }
        #pragma unroll
        for (int nt = 0; nt < 4; ++nt) {
            fbh[nt] = *reinterpret_cast<const s16x8*>(&Bh[q][nt * 16 + m][0]);
            fbl[nt] = *reinterpret_cast<const s16x8*>(&Bl[q][nt * 16 + m][0]);
        }
        #pragma unroll
        for (int mt = 0; mt < 2; ++mt)
            #pragma unroll
            for (int nt = 0; nt < 4; ++nt) {
                acc[mt][nt] = __builtin_amdgcn_mfma_f32_16x16x32_bf16(fah[mt], fbh[nt], acc[mt][nt], 0, 0, 0);
                acc[mt][nt] = __builtin_amdgcn_mfma_f32_16x16x32_bf16(fah[mt], fbl[nt], acc[mt][nt], 0, 0, 0);
                acc[mt][nt] = __builtin_amdgcn_mfma_f32_16x16x32_bf16(fal[mt], fbh[nt], acc[mt][nt], 0, 0, 0);
            }
    }

    // epilogue: C/D layout col=lane&15, row=q*4+reg
    #pragma unroll
    for (int mt = 0; mt < 2; ++mt) {
        #pragma unroll
        for (int nt = 0; nt < 4; ++nt) {
            #pragma unroll
            for (int r = 0; r < 4; ++r) {
                const int lr = w * 32 + mt * 16 + q * 4 + r;
                const int lc = nt * 16 + m;
                const float d2 = sqA[lr] + sqB[lc] - 2.0f * acc[mt][nt][r];
                distp[(size_t)(row0 + lr) * NN + col0 + lc] = (d2 > 0.f) ? sqrtf(d2) : 0.f;
            }
        }
    }
}

// ---------------- kernel 3: per-row scans + window lookup ----------------
__device__ __forceinline__ void lse_combine(float& m, float& s, float nm, float ns) {
    if (nm == NEGINF) return;
    if (m == NEGINF) { m = nm; s = ns; return; }
    if (nm <= m) { s += ns * expf(nm - m); }
    else         { s = ns + s * expf(m - nm); m = nm; }
}

__device__ __forceinline__ float lse_fin(float m, float s) {
    return (m == NEGINF) ? NEGINF : (m + logf(s));
}

__device__ __forceinline__ float lse_pair(float a, float b) {
    if (a == NEGINF) return b;
    if (b == NEGINF) return a;
    const float mx = fmaxf(a, b);
    const float mn = fminf(a, b);
    return mx + log1pf(expf(mn - mx));
}

__global__ __launch_bounds__(256) void row_kernel(const float* __restrict__ distp,
                                                  const float* __restrict__ labels,
                                                  const float* __restrict__ slab,
                                                  const int* __restrict__ inv,
                                                  double* __restrict__ rowval) {
    __shared__ float key[NN];
    __shared__ float val[NN];
    __shared__ float Plog[NN + 1];
    __shared__ float Slog[NN + 1];
    __shared__ float wM[4], wS[4], wM2[4], wS2[4];
    __shared__ double wD[4], wL[4];

    const int i = blockIdx.x;
    const int t = threadIdx.x;
    const int lane = t & 63;
    const int w = t >> 6;
    const int pos_i = inv[i];
    const float x = labels[i & (BB - 1)];
    const float negInvT = -1.0f / 0.07f;
    const float* drow = &distp[(size_t)i * NN];

    // ---- load row (label-sorted columns), build key/val ----
    double dsum = 0.0;
    #pragma unroll
    for (int e = 0; e < 2; ++e) {
        const int p4 = t + e * NT;
        const int p = p4 * 4;
        const float4 d4 = reinterpret_cast<const float4*>(drow)[p4];
        const float4 l4 = reinterpret_cast<const float4*>(slab)[p4];
        const float dv[4] = {d4.x, d4.y, d4.z, d4.w};
        const float lv[4] = {l4.x, l4.y, l4.z, l4.w};
        #pragma unroll
        for (int c = 0; c < 4; ++c) {
            const int pc = p + c;
            key[pc] = fabsf(lv[c] - x);
            if (pc == pos_i) {
                val[pc] = NEGINF;
            } else {
                val[pc] = dv[c] * negInvT;
                dsum += (double)dv[c];
            }
        }
    }
    __syncthreads();   // B1: key/val ready

    const int cb = t * 8;
    float em[8], es[8];

    // ---- prefix LSE ----
    {
        float m = NEGINF, s = 0.f;
        #pragma unroll
        for (int jj = 0; jj < 8; ++jj) {
            em[jj] = m; es[jj] = s;
            const float vv = val[cb + jj];
            if (vv != NEGINF) {
                if (m == NEGINF) { m = vv; s = 1.f; }
                else if (vv <= m) { s += expf(vv - m); }
                else { s = s * expf(m - vv) + 1.f; m = vv; }
            }
        }
        float im = m, is = s;
        #pragma unroll
        for (int st = 1; st < 64; st <<= 1) {
            const float nm = __shfl_up(im, st);
            const float ns = __shfl_up(is, st);
            if (lane >= st) lse_combine(im, is, nm, ns);
        }
        float xm = __shfl_up(im, 1);
        float xs = __shfl_up(is, 1);
        if (lane == 0) { xm = NEGINF; xs = 0.f; }
        if (lane == 63) { wM[w] = im; wS[w] = is; }
        __syncthreads();   // B2
        #pragma unroll
        for (int ww = 0; ww < 3; ++ww)
            if (ww < w) lse_combine(xm, xs, wM[ww], wS[ww]);
        #pragma unroll
        for (int jj = 0; jj < 8; ++jj) {
            float m2 = em[jj], s2 = es[jj];
            lse_combine(m2, s2, xm, xs);
            Plog[cb + jj] = lse_fin(m2, s2);
        }
        if (t == 0) {
            float m2 = NEGINF, s2 = 0.f;
            #pragma unroll
            for (int ww = 0; ww < 4; ++ww) lse_combine(m2, s2, wM[ww], wS[ww]);
            Plog[NN] = lse_fin(m2, s2);
        }
    }

    // ---- suffix LSE ----
    {
        float m = NEGINF, s = 0.f;
        #pragma unroll
        for (int jj = 7; jj >= 0; --jj) {
            const float vv = val[cb + jj];
            if (vv != NEGINF) {
                if (m == NEGINF) { m = vv; s = 1.f; }
                else if (vv <= m) { s += expf(vv - m); }
                else { s = s * expf(m - vv) + 1.f; m = vv; }
            }
            em[jj] = m; es[jj] = s;
        }
        float im = m, is = s;
        #pragma unroll
        for (int st = 1; st < 64; st <<= 1) {
            const float nm = __shfl_down(im, st);
            const float ns = __shfl_down(is, st);
            if (lane + st < 64) lse_combine(im, is, nm, ns);
        }
        float xm = __shfl_down(im, 1);
        float xs = __shfl_down(is, 1);
        if (lane == 63) { xm = NEGINF; xs = 0.f; }
        if (lane == 0) { wM2[w] = im; wS2[w] = is; }
        __syncthreads();   // B3
        #pragma unroll
        for (int ww = 1; ww < 4; ++ww)
            if (ww > w) lse_combine(xm, xs, wM2[ww], wS2[ww]);
        #pragma unroll
        for (int jj = 0; jj < 8; ++jj) {
            float m2 = em[jj], s2 = es[jj];
            lse_combine(m2, s2, xm, xs);
            Slog[cb + jj] = lse_fin(m2, s2);
        }
        if (t == 0) Slog[NN] = NEGINF;
    }
    __syncthreads();   // B4

    // ---- per element: [L,R) = {key < d}; negative = P[L] (+) S[R] ----
    double lnsum = 0.0;
    #pragma unroll
    for (int jj = 0; jj < 8; ++jj) {
        const int p = cb + jj;
        if (p == pos_i) continue;
        const float d = key[p];
        int lo = 0, hi = pos_i;
        while (lo < hi) {
            const int mid = (lo + hi) >> 1;
            if (key[mid] < d) hi = mid; else lo = mid + 1;
        }
        const int L = lo;
        lo = pos_i; hi = NN;
        while (lo < hi) {
            const int mid = (lo + hi) >> 1;
            if (key[mid] >= d) hi = mid; else lo = mid + 1;
        }
        const int R = lo;
        lnsum += (double)lse_pair(Plog[L], Slog[R]);
    }

    #pragma unroll
    for (int st = 32; st > 0; st >>= 1) {
        dsum  += __shfl_down(dsum, st);
        lnsum += __shfl_down(lnsum, st);
    }
    if (lane == 0) { wD[w] = dsum; wL[w] = lnsum; }
    __syncthreads();   // B5
    if (t == 0) {
        const double td = wD[0] + wD[1] + wD[2] + wD[3];
        const double tl = wL[0] + wL[1] + wL[2] + wL[3];
        rowval[i] = (-td / 0.07) - tl;
    }
}

// ---------------- kernel 4: final mean ----------------
__global__ __launch_bounds__(256) void finalize_kernel(const double* __restrict__ rowval,
                                                       float* __restrict__ out) {
    __shared__ double red[NT];
    const int t = threadIdx.x;
    double s = 0.0;
    for (int j = t; j < NN; j += NT) s += rowval[j];
    red[t] = s;
    __syncthreads();
    for (int ofs = NT / 2; ofs > 0; ofs >>= 1) {
        if (t < ofs) red[t] += red[t + ofs];
        __syncthreads();
    }
    if (t == 0) {
        out[0] = (float)(-red[0] / ((double)NN * (double)(NN - 1)));
    }
}

extern "C" void kernel_launch(void* const* d_in, const int* in_sizes, int n_in,
                              void* d_out, int out_size, void* d_ws, size_t ws_size,
                              hipStream_t stream) {
    const float* features = (const float*)d_in[0];  // [1024, 2, 512] fp32
    const float* labels   = (const float*)d_in[1];  // [1024] fp32
    float* out = (float*)d_out;

    char* ws = (char*)d_ws;
    size_t off = 0;
    float*  sq     = (float*) (ws + off); off += NN * sizeof(float);
    float*  slab   = (float*) (ws + off); off += NN * sizeof(float);
    int*    sj     = (int*)   (ws + off); off += NN * sizeof(int);
    int*    inv    = (int*)   (ws + off); off += NN * sizeof(int);
    double* rowval = (double*)(ws + off); off += NN * sizeof(double);
    ushort* Ahi    = (ushort*)(ws + off); off += (size_t)NN * DD * sizeof(ushort);
    ushort* Alo    = (ushort*)(ws + off); off += (size_t)NN * DD * sizeof(ushort);
    float*  distp  = (float*) (ws + off); off += (size_t)NN * NN * sizeof(float);

    sort_labels_kernel<<<1, NT, 0, stream>>>(labels, slab, sj, inv);
    prep_split_kernel<<<NN / 4, NT, 0, stream>>>(features, Ahi, Alo, sq);
    dim3 ggrid(NN / TN, NN / TM);
    gemm_dist_kernel<<<ggrid, NT, 0, stream>>>(Ahi, Alo, sq, sj, distp);
    row_kernel<<<NN, NT, 0, stream>>>(distp, labels, slab, inv, rowval);
    finalize_kernel<<<1, NT, 0, stream>>>(rowval, out);
}

// Round 5
// 187.740 us; speedup vs baseline: 1.8988x; 1.0048x over previous
//
#include <hip/hip_runtime.h>
#include <math.h>

// SupCR loss, MI355X. Round 5: row_kernel latency attack.
//  - val[] LDS array removed (vals live in registers; LDS 33->24.7 KB, 6 blk/CU).
//  - per element, the same-side window boundary is a tie-run scan (1-2 probes);
//    only the cross-segment boundary is searched, extremes full + middles
//    bracketed (monotone in p within a thread's 8 contiguous elements).
//    Produces bit-identical L/R to the full binary searches of round 4.
// GEMM (3-term bf16-split MFMA), label sort, scans unchanged from round 4.

#define NN 2048      // N = B*V
#define BB 1024      // B
#define DD 512       // D
#define NT 256       // threads per block
#define NEGINF (-INFINITY)

typedef short s16x8 __attribute__((ext_vector_type(8)));
typedef float f32x4 __attribute__((ext_vector_type(4)));

// row i of the virtual cf matrix lives at F + ((i%B)*2 + i/B)*D
__device__ __forceinline__ const float* cf_row(const float* F, int i) {
    return F + ((size_t)(i & (BB - 1)) * 2 + (size_t)(i >> 10)) * DD;
}

__device__ __forceinline__ unsigned bf_rne(float x) {
    const unsigned u = __float_as_uint(x);
    return (u + 0x7FFFu + ((u >> 16) & 1u)) >> 16;
}
__device__ __forceinline__ float bf_val(unsigned h) {
    return __uint_as_float(h << 16);
}

// ---------------- kernel 0: sort labels once ----------------
__global__ __launch_bounds__(256) void sort_labels_kernel(const float* __restrict__ labels,
                                                          float* __restrict__ slab,
                                                          int* __restrict__ sj,
                                                          int* __restrict__ inv) {
    __shared__ float kk[BB];
    __shared__ int   id[BB];
    const int t = threadIdx.x;
    #pragma unroll
    for (int e = 0; e < 4; ++e) { const int p = t + e * NT; kk[p] = labels[p]; id[p] = p; }
    for (int k = 2; k <= BB; k <<= 1) {
        for (int j = k >> 1; j > 0; j >>= 1) {
            __syncthreads();
            #pragma unroll
            for (int e = 0; e < 4; ++e) {
                const int idx = t + e * NT;
                const int ixj = idx ^ j;
                if (ixj > idx) {
                    const float k1 = kk[idx], k2 = kk[ixj];
                    const bool up = ((idx & k) == 0);
                    if (up ? (k1 > k2) : (k1 < k2)) {
                        kk[idx] = k2; kk[ixj] = k1;
                        const int i1 = id[idx]; id[idx] = id[ixj]; id[ixj] = i1;
                    }
                }
            }
        }
    }
    __syncthreads();
    #pragma unroll
    for (int e = 0; e < 4; ++e) {
        const int p = t + e * NT;
        const float lv = kk[p];
        const int b = id[p];
        slab[2 * p] = lv; slab[2 * p + 1] = lv;
        sj[2 * p] = b;    sj[2 * p + 1] = b + BB;
        inv[b] = 2 * p;   inv[b + BB] = 2 * p + 1;
    }
}

// ---------------- kernel 1: bf16 hi/lo split + squared norms ----------------
__global__ __launch_bounds__(256) void prep_split_kernel(const float* __restrict__ F,
                                                         ushort* __restrict__ Ahi,
                                                         ushort* __restrict__ Alo,
                                                         float* __restrict__ sq) {
    const int t = threadIdx.x;
    const int lane = t & 63;
    const int w = t >> 6;
    const int i = blockIdx.x * 4 + w;
    const float* src = cf_row(F, i);
    const float4 v0 = reinterpret_cast<const float4*>(src)[lane];
    const float4 v1 = reinterpret_cast<const float4*>(src)[lane + 64];
    float ss = v0.x * v0.x + v0.y * v0.y + v0.z * v0.z + v0.w * v0.w
             + v1.x * v1.x + v1.y * v1.y + v1.z * v1.z + v1.w * v1.w;
    #pragma unroll
    for (int st = 32; st > 0; st >>= 1) ss += __shfl_down(ss, st);
    if (lane == 0) sq[i] = ss;

    const float a[8] = {v0.x, v0.y, v0.z, v0.w, v1.x, v1.y, v1.z, v1.w};
    ushort h[8], l[8];
    #pragma unroll
    for (int e = 0; e < 8; ++e) {
        const unsigned hb = bf_rne(a[e]);
        h[e] = (ushort)hb;
        l[e] = (ushort)bf_rne(a[e] - bf_val(hb));
    }
    const size_t base = (size_t)i * DD;
    *reinterpret_cast<ushort4*>(&Ahi[base + lane * 4])       = make_ushort4(h[0], h[1], h[2], h[3]);
    *reinterpret_cast<ushort4*>(&Ahi[base + 256 + lane * 4]) = make_ushort4(h[4], h[5], h[6], h[7]);
    *reinterpret_cast<ushort4*>(&Alo[base + lane * 4])       = make_ushort4(l[0], l[1], l[2], l[3]);
    *reinterpret_cast<ushort4*>(&Alo[base + 256 + lane * 4]) = make_ushort4(l[4], l[5], l[6], l[7]);
}

// ---------------- kernel 2: MFMA dist, 128x64 tile ----------------
#define TM 128
#define TN 64
#define TK 32
__global__ __launch_bounds__(256) void gemm_dist_kernel(const ushort* __restrict__ Ahi,
                                                        const ushort* __restrict__ Alo,
                                                        const float* __restrict__ sq,
                                                        const int* __restrict__ sj,
                                                        float* __restrict__ distp) {
    __shared__ ushort Ah[4][TM][8];
    __shared__ ushort Al[4][TM][8];
    __shared__ ushort Bh[4][TN][8];
    __shared__ ushort Bl[4][TN][8];
    __shared__ int   sjc[TN];
    __shared__ float sqA[TM];
    __shared__ float sqB[TN];

    const int t = threadIdx.x;
    const int lane = t & 63;
    const int w = t >> 6;
    const int row0 = blockIdx.y * TM;
    const int col0 = blockIdx.x * TN;

    if (t < TN) {
        const int s = sj[col0 + t];
        sjc[t] = s;
        sqB[t] = sq[s];
    } else if (t < TN + TM) {
        sqA[t - TN] = sq[row0 + (t - TN)];
    }

    f32x4 acc[2][4] = {};
    const int m = lane & 15;
    const int q = lane >> 4;

    for (int kt = 0; kt < DD / TK; ++kt) {
        __syncthreads();
        for (int c = t; c < TM * 4; c += NT) {
            const int row = c >> 2, cq = c & 3;
            const size_t g = (size_t)(row0 + row) * DD + kt * TK + cq * 8;
            *reinterpret_cast<int4*>(&Ah[cq][row][0]) = *reinterpret_cast<const int4*>(&Ahi[g]);
            *reinterpret_cast<int4*>(&Al[cq][row][0]) = *reinterpret_cast<const int4*>(&Alo[g]);
        }
        for (int c = t; c < TN * 4; c += NT) {
            const int row = c >> 2, cq = c & 3;
            const size_t g = (size_t)sjc[row] * DD + kt * TK + cq * 8;
            *reinterpret_cast<int4*>(&Bh[cq][row][0]) = *reinterpret_cast<const int4*>(&Ahi[g]);
            *reinterpret_cast<int4*>(&Bl[cq][row][0]) = *reinterpret_cast<const int4*>(&Alo[g]);
        }
        __syncthreads();

        s16x8 fah[2], fal[2], fbh[4], fbl[4];
        #pragma unroll
        for (int mt = 0; mt < 2; ++mt) {
            fah[mt] = *reinterpret_cast<const s16x8*>(&Ah[q][w * 32 + mt * 16 + m][0]);
            fal[mt] = *reinterpret_cast<const s16x8*>(&Al[q][w * 32 + mt * 16 + m][0]);
        }
        #pragma unroll
        for (int nt = 0; nt < 4; ++nt) {
            fbh[nt] = *reinterpret_cast<const s16x8*>(&Bh[q][nt * 16 + m][0]);
            fbl[nt] = *reinterpret_cast<const s16x8*>(&Bl[q][nt * 16 + m][0]);
        }
        #pragma unroll
        for (int mt = 0; mt < 2; ++mt)
            #pragma unroll
            for (int nt = 0; nt < 4; ++nt) {
                acc[mt][nt] = __builtin_amdgcn_mfma_f32_16x16x32_bf16(fah[mt], fbh[nt], acc[mt][nt], 0, 0, 0);
                acc[mt][nt] = __builtin_amdgcn_mfma_f32_16x16x32_bf16(fah[mt], fbl[nt], acc[mt][nt], 0, 0, 0);
                acc[mt][nt] = __builtin_amdgcn_mfma_f32_16x16x32_bf16(fal[mt], fbh[nt], acc[mt][nt], 0, 0, 0);
            }
    }

    #pragma unroll
    for (int mt = 0; mt < 2; ++mt) {
        #pragma unroll
        for (int nt = 0; nt < 4; ++nt) {
            #pragma unroll
            for (int r = 0; r < 4; ++r) {
                const int lr = w * 32 + mt * 16 + q * 4 + r;
                const int lc = nt * 16 + m;
                const float d2 = sqA[lr] + sqB[lc] - 2.0f * acc[mt][nt][r];
                distp[(size_t)(row0 + lr) * NN + col0 + lc] = (d2 > 0.f) ? sqrtf(d2) : 0.f;
            }
        }
    }
}

// ---------------- kernel 3: per-row scans + window lookup ----------------
__device__ __forceinline__ void lse_combine(float& m, float& s, float nm, float ns) {
    if (nm == NEGINF) return;
    if (m == NEGINF) { m = nm; s = ns; return; }
    if (nm <= m) { s += ns * expf(nm - m); }
    else         { s = ns + s * expf(m - nm); m = nm; }
}

__device__ __forceinline__ float lse_fin(float m, float s) {
    return (m == NEGINF) ? NEGINF : (m + logf(s));
}

__device__ __forceinline__ float lse_pair(float a, float b) {
    if (a == NEGINF) return b;
    if (b == NEGINF) return a;
    const float mx = fmaxf(a, b);
    const float mn = fminf(a, b);
    return mx + log1pf(expf(mn - mx));
}

// first idx in [lo,hi) with key[idx] >= d (right segment: keys non-decreasing)
__device__ __forceinline__ int bs_right(const float* key, float d, int lo, int hi) {
    while (lo < hi) {
        const int mid = (lo + hi) >> 1;
        if (key[mid] >= d) hi = mid; else lo = mid + 1;
    }
    return lo;
}
// first idx in [lo,hi) with key[idx] < d (left segment: keys non-increasing)
__device__ __forceinline__ int bs_left(const float* key, float d, int lo, int hi) {
    while (lo < hi) {
        const int mid = (lo + hi) >> 1;
        if (key[mid] < d) hi = mid; else lo = mid + 1;
    }
    return lo;
}

__global__ __launch_bounds__(256) void row_kernel(const float* __restrict__ distp,
                                                  const float* __restrict__ labels,
                                                  const float* __restrict__ slab,
                                                  const int* __restrict__ inv,
                                                  double* __restrict__ rowval) {
    __shared__ float key[NN];
    __shared__ float Plog[NN + 1];
    __shared__ float Slog[NN + 1];
    __shared__ float wM[4], wS[4], wM2[4], wS2[4];
    __shared__ double wD[4], wL[4];

    const int i = blockIdx.x;
    const int t = threadIdx.x;
    const int lane = t & 63;
    const int w = t >> 6;
    const int pos_i = inv[i];
    const float x = labels[i & (BB - 1)];
    const float negInvT = -1.0f / 0.07f;
    const float* drow = &distp[(size_t)i * NN];

    // ---- keys (coalesced strided), vals (thread-own 8, registers) ----
    #pragma unroll
    for (int e = 0; e < 2; ++e) {
        const int p4 = t + e * NT;
        const float4 l4 = reinterpret_cast<const float4*>(slab)[p4];
        key[p4 * 4 + 0] = fabsf(l4.x - x);
        key[p4 * 4 + 1] = fabsf(l4.y - x);
        key[p4 * 4 + 2] = fabsf(l4.z - x);
        key[p4 * 4 + 3] = fabsf(l4.w - x);
    }
    const int cb = t * 8;
    float v[8];
    double dsum = 0.0;
    #pragma unroll
    for (int e = 0; e < 2; ++e) {
        const float4 d4 = reinterpret_cast<const float4*>(drow)[2 * t + e];
        const float dv[4] = {d4.x, d4.y, d4.z, d4.w};
        #pragma unroll
        for (int c = 0; c < 4; ++c) {
            const int pc = cb + e * 4 + c;
            if (pc == pos_i) {
                v[e * 4 + c] = NEGINF;
            } else {
                v[e * 4 + c] = dv[c] * negInvT;
                dsum += (double)dv[c];
            }
        }
    }
    __syncthreads();   // B1: keys ready

    float em[8], es[8];

    // ---- prefix LSE ----
    {
        float m = NEGINF, s = 0.f;
        #pragma unroll
        for (int jj = 0; jj < 8; ++jj) {
            em[jj] = m; es[jj] = s;
            const float vv = v[jj];
            if (vv != NEGINF) {
                if (m == NEGINF) { m = vv; s = 1.f; }
                else if (vv <= m) { s += expf(vv - m); }
                else { s = s * expf(m - vv) + 1.f; m = vv; }
            }
        }
        float im = m, is = s;
        #pragma unroll
        for (int st = 1; st < 64; st <<= 1) {
            const float nm = __shfl_up(im, st);
            const float ns = __shfl_up(is, st);
            if (lane >= st) lse_combine(im, is, nm, ns);
        }
        float xm = __shfl_up(im, 1);
        float xs = __shfl_up(is, 1);
        if (lane == 0) { xm = NEGINF; xs = 0.f; }
        if (lane == 63) { wM[w] = im; wS[w] = is; }
        __syncthreads();   // B2
        #pragma unroll
        for (int ww = 0; ww < 3; ++ww)
            if (ww < w) lse_combine(xm, xs, wM[ww], wS[ww]);
        #pragma unroll
        for (int jj = 0; jj < 8; ++jj) {
            float m2 = em[jj], s2 = es[jj];
            lse_combine(m2, s2, xm, xs);
            Plog[cb + jj] = lse_fin(m2, s2);
        }
        if (t == 0) {
            float m2 = NEGINF, s2 = 0.f;
            #pragma unroll
            for (int ww = 0; ww < 4; ++ww) lse_combine(m2, s2, wM[ww], wS[ww]);
            Plog[NN] = lse_fin(m2, s2);
        }
    }

    // ---- suffix LSE ----
    {
        float m = NEGINF, s = 0.f;
        #pragma unroll
        for (int jj = 7; jj >= 0; --jj) {
            const float vv = v[jj];
            if (vv != NEGINF) {
                if (m == NEGINF) { m = vv; s = 1.f; }
                else if (vv <= m) { s += expf(vv - m); }
                else { s = s * expf(m - vv) + 1.f; m = vv; }
            }
            em[jj] = m; es[jj] = s;
        }
        float im = m, is = s;
        #pragma unroll
        for (int st = 1; st < 64; st <<= 1) {
            const float nm = __shfl_down(im, st);
            const float ns = __shfl_down(is, st);
            if (lane + st < 64) lse_combine(im, is, nm, ns);
        }
        float xm = __shfl_down(im, 1);
        float xs = __shfl_down(is, 1);
        if (lane == 63) { xm = NEGINF; xs = 0.f; }
        if (lane == 0) { wM2[w] = im; wS2[w] = is; }
        __syncthreads();   // B3
        #pragma unroll
        for (int ww = 1; ww < 4; ++ww)
            if (ww > w) lse_combine(xm, xs, wM2[ww], wS2[ww]);
        #pragma unroll
        for (int jj = 0; jj < 8; ++jj) {
            float m2 = em[jj], s2 = es[jj];
            lse_combine(m2, s2, xm, xs);
            Slog[cb + jj] = lse_fin(m2, s2);
        }
        if (t == 0) Slog[NN] = NEGINF;
    }
    __syncthreads();   // B4

    // ---- windows: same-side boundary = tie scan; cross boundary = bracketed bs
    double lnsum = 0.0;
    const int a = cb, b = cb + 7;
    // left-side group [a, le]
    {
        const int le = (pos_i - 1 < b) ? pos_i - 1 : b;
        if (a <= le) {
            const float da = key[a];
            const int Ra = bs_right(key, da, pos_i, NN);
            int Rl = Ra;
            if (le > a) Rl = bs_right(key, key[le], pos_i, Ra);
            for (int p = a; p <= le; ++p) {
                const float d = key[p];
                int R;
                if (p == a) R = Ra;
                else if (p == le) R = Rl;
                else R = bs_right(key, d, Rl, Ra);
                int L = p + 1;                       // tie-run end (left keys desc)
                while (L < pos_i && key[L] == d) ++L;
                lnsum += (double)lse_pair(Plog[L], Slog[R]);
            }
        }
    }
    // right-side group [rs, b]
    {
        const int rs = (pos_i + 1 > a) ? pos_i + 1 : a;
        if (rs <= b) {
            const float dr = key[rs];
            const int Lr = bs_left(key, dr, 0, pos_i);
            int Lb = Lr;
            if (b > rs) Lb = bs_left(key, key[b], 0, Lr);
            for (int p = rs; p <= b; ++p) {
                const float d = key[p];
                int L;
                if (p == rs) L = Lr;
                else if (p == b) L = Lb;
                else L = bs_left(key, d, Lb, Lr);
                int R = p;                            // tie-run start (right keys asc)
                while (R > pos_i && key[R - 1] == d) --R;
                lnsum += (double)lse_pair(Plog[L], Slog[R]);
            }
        }
    }

    #pragma unroll
    for (int st = 32; st > 0; st >>= 1) {
        dsum  += __shfl_down(dsum, st);
        lnsum += __shfl_down(lnsum, st);
    }
    if (lane == 0) { wD[w] = dsum; wL[w] = lnsum; }
    __syncthreads();   // B5
    if (t == 0) {
        const double td = wD[0] + wD[1] + wD[2] + wD[3];
        const double tl = wL[0] + wL[1] + wL[2] + wL[3];
        rowval[i] = (-td / 0.07) - tl;
    }
}

// ---------------- kernel 4: final mean ----------------
__global__ __launch_bounds__(256) void finalize_kernel(const double* __restrict__ rowval,
                                                       float* __restrict__ out) {
    __shared__ double red[NT];
    const int t = threadIdx.x;
    double s = 0.0;
    for (int j = t; j < NN; j += NT) s += rowval[j];
    red[t] = s;
    __syncthreads();
    for (int ofs = NT / 2; ofs > 0; ofs >>= 1) {
        if (t < ofs) red[t] += red[t + ofs];
        __syncthreads();
    }
    if (t == 0) {
        out[0] = (float)(-red[0] / ((double)NN * (double)(NN - 1)));
    }
}

extern "C" void kernel_launch(void* const* d_in, const int* in_sizes, int n_in,
                              void* d_out, int out_size, void* d_ws, size_t ws_size,
                              hipStream_t stream) {
    const float* features = (const float*)d_in[0];  // [1024, 2, 512] fp32
    const float* labels   = (const float*)d_in[1];  // [1024] fp32
    float* out = (float*)d_out;

    char* ws = (char*)d_ws;
    size_t off = 0;
    float*  sq     = (float*) (ws + off); off += NN * sizeof(float);
    float*  slab   = (float*) (ws + off); off += NN * sizeof(float);
    int*    sj     = (int*)   (ws + off); off += NN * sizeof(int);
    int*    inv    = (int*)   (ws + off); off += NN * sizeof(int);
    double* rowval = (double*)(ws + off); off += NN * sizeof(double);
    ushort* Ahi    = (ushort*)(ws + off); off += (size_t)NN * DD * sizeof(ushort);
    ushort* Alo    = (ushort*)(ws + off); off += (size_t)NN * DD * sizeof(ushort);
    float*  distp  = (float*) (ws + off); off += (size_t)NN * NN * sizeof(float);

    sort_labels_kernel<<<1, NT, 0, stream>>>(labels, slab, sj, inv);
    prep_split_kernel<<<NN / 4, NT, 0, stream>>>(features, Ahi, Alo, sq);
    dim3 ggrid(NN / TN, NN / TM);
    gemm_dist_kernel<<<ggrid, NT, 0, stream>>>(Ahi, Alo, sq, sj, distp);
    row_kernel<<<NN, NT, 0, stream>>>(distp, labels, slab, inv, rowval);
    finalize_kernel<<<1, NT, 0, stream>>>(rowval, out);
}

// Round 6
// 161.333 us; speedup vs baseline: 2.2096x; 1.1637x over previous
//
#include <hip/hip_runtime.h>
#include <math.h>

// SupCR loss, MI355X. Round 6: row_kernel in linear-double space.
//  - One row-wide max M; e_q = exp(v_q - M) computed as t*t with
//    t = __expf((v-M)/2) (hw exp, underflow-safe to e^-170 in double).
//  - Prefix/suffix scans are plain double adds (no lse branches / libm).
//  - log(negative) = M + dlog(Pd[L] + Sd[R]); dlog = exponent bits + __logf.
//  - sort_labels at 512 threads (halves serial bitonic ladder).
// GEMM (3-term bf16-split MFMA) and window search logic unchanged.

#define NN 2048      // N = B*V
#define BB 1024      // B
#define DD 512       // D
#define NT 256       // threads per block
#define NEGINF (-INFINITY)

typedef short s16x8 __attribute__((ext_vector_type(8)));
typedef float f32x4 __attribute__((ext_vector_type(4)));

// row i of the virtual cf matrix lives at F + ((i%B)*2 + i/B)*D
__device__ __forceinline__ const float* cf_row(const float* F, int i) {
    return F + ((size_t)(i & (BB - 1)) * 2 + (size_t)(i >> 10)) * DD;
}

__device__ __forceinline__ unsigned bf_rne(float x) {
    const unsigned u = __float_as_uint(x);
    return (u + 0x7FFFu + ((u >> 16) & 1u)) >> 16;
}
__device__ __forceinline__ float bf_val(unsigned h) {
    return __uint_as_float(h << 16);
}

// log of a positive normal double: exponent + hw log of mantissa
__device__ __forceinline__ float dlogf(double s) {
    const unsigned long long b = __double_as_longlong(s);
    const int e2 = (int)(b >> 52) - 1023;
    const double md = __longlong_as_double((b & 0xFFFFFFFFFFFFFULL) | 0x3FF0000000000000ULL);
    return (float)e2 * 0.6931471805599453f + __logf((float)md);
}

// ---------------- kernel 0: sort labels once (512 thr, 1 pair/stage) --------
__global__ __launch_bounds__(512) void sort_labels_kernel(const float* __restrict__ labels,
                                                          float* __restrict__ slab,
                                                          int* __restrict__ sj,
                                                          int* __restrict__ inv) {
    __shared__ float kk[BB];
    __shared__ int   id[BB];
    const int t = threadIdx.x;
    #pragma unroll
    for (int e = 0; e < 2; ++e) { const int p = t + e * 512; kk[p] = labels[p]; id[p] = p; }
    for (int k = 2; k <= BB; k <<= 1) {
        for (int j = k >> 1; j > 0; j >>= 1) {
            __syncthreads();
            #pragma unroll
            for (int e = 0; e < 2; ++e) {
                const int idx = t + e * 512;
                const int ixj = idx ^ j;
                if (ixj > idx) {
                    const float k1 = kk[idx], k2 = kk[ixj];
                    const bool up = ((idx & k) == 0);
                    if (up ? (k1 > k2) : (k1 < k2)) {
                        kk[idx] = k2; kk[ixj] = k1;
                        const int i1 = id[idx]; id[idx] = id[ixj]; id[ixj] = i1;
                    }
                }
            }
        }
    }
    __syncthreads();
    #pragma unroll
    for (int e = 0; e < 2; ++e) {
        const int p = t + e * 512;
        const float lv = kk[p];
        const int b = id[p];
        slab[2 * p] = lv; slab[2 * p + 1] = lv;
        sj[2 * p] = b;    sj[2 * p + 1] = b + BB;
        inv[b] = 2 * p;   inv[b + BB] = 2 * p + 1;
    }
}

// ---------------- kernel 1: bf16 hi/lo split + squared norms ----------------
__global__ __launch_bounds__(256) void prep_split_kernel(const float* __restrict__ F,
                                                         ushort* __restrict__ Ahi,
                                                         ushort* __restrict__ Alo,
                                                         float* __restrict__ sq) {
    const int t = threadIdx.x;
    const int lane = t & 63;
    const int w = t >> 6;
    const int i = blockIdx.x * 4 + w;
    const float* src = cf_row(F, i);
    const float4 v0 = reinterpret_cast<const float4*>(src)[lane];
    const float4 v1 = reinterpret_cast<const float4*>(src)[lane + 64];
    float ss = v0.x * v0.x + v0.y * v0.y + v0.z * v0.z + v0.w * v0.w
             + v1.x * v1.x + v1.y * v1.y + v1.z * v1.z + v1.w * v1.w;
    #pragma unroll
    for (int st = 32; st > 0; st >>= 1) ss += __shfl_down(ss, st);
    if (lane == 0) sq[i] = ss;

    const float a[8] = {v0.x, v0.y, v0.z, v0.w, v1.x, v1.y, v1.z, v1.w};
    ushort h[8], l[8];
    #pragma unroll
    for (int e = 0; e < 8; ++e) {
        const unsigned hb = bf_rne(a[e]);
        h[e] = (ushort)hb;
        l[e] = (ushort)bf_rne(a[e] - bf_val(hb));
    }
    const size_t base = (size_t)i * DD;
    *reinterpret_cast<ushort4*>(&Ahi[base + lane * 4])       = make_ushort4(h[0], h[1], h[2], h[3]);
    *reinterpret_cast<ushort4*>(&Ahi[base + 256 + lane * 4]) = make_ushort4(h[4], h[5], h[6], h[7]);
    *reinterpret_cast<ushort4*>(&Alo[base + lane * 4])       = make_ushort4(l[0], l[1], l[2], l[3]);
    *reinterpret_cast<ushort4*>(&Alo[base + 256 + lane * 4]) = make_ushort4(l[4], l[5], l[6], l[7]);
}

// ---------------- kernel 2: MFMA dist, 128x64 tile ----------------
#define TM 128
#define TN 64
#define TK 32
__global__ __launch_bounds__(256) void gemm_dist_kernel(const ushort* __restrict__ Ahi,
                                                        const ushort* __restrict__ Alo,
                                                        const float* __restrict__ sq,
                                                        const int* __restrict__ sj,
                                                        float* __restrict__ distp) {
    __shared__ ushort Ah[4][TM][8];
    __shared__ ushort Al[4][TM][8];
    __shared__ ushort Bh[4][TN][8];
    __shared__ ushort Bl[4][TN][8];
    __shared__ int   sjc[TN];
    __shared__ float sqA[TM];
    __shared__ float sqB[TN];

    const int t = threadIdx.x;
    const int lane = t & 63;
    const int w = t >> 6;
    const int row0 = blockIdx.y * TM;
    const int col0 = blockIdx.x * TN;

    if (t < TN) {
        const int s = sj[col0 + t];
        sjc[t] = s;
        sqB[t] = sq[s];
    } else if (t < TN + TM) {
        sqA[t - TN] = sq[row0 + (t - TN)];
    }

    f32x4 acc[2][4] = {};
    const int m = lane & 15;
    const int q = lane >> 4;

    for (int kt = 0; kt < DD / TK; ++kt) {
        __syncthreads();
        for (int c = t; c < TM * 4; c += NT) {
            const int row = c >> 2, cq = c & 3;
            const size_t g = (size_t)(row0 + row) * DD + kt * TK + cq * 8;
            *reinterpret_cast<int4*>(&Ah[cq][row][0]) = *reinterpret_cast<const int4*>(&Ahi[g]);
            *reinterpret_cast<int4*>(&Al[cq][row][0]) = *reinterpret_cast<const int4*>(&Alo[g]);
        }
        for (int c = t; c < TN * 4; c += NT) {
            const int row = c >> 2, cq = c & 3;
            const size_t g = (size_t)sjc[row] * DD + kt * TK + cq * 8;
            *reinterpret_cast<int4*>(&Bh[cq][row][0]) = *reinterpret_cast<const int4*>(&Ahi[g]);
            *reinterpret_cast<int4*>(&Bl[cq][row][0]) = *reinterpret_cast<const int4*>(&Alo[g]);
        }
        __syncthreads();

        s16x8 fah[2], fal[2], fbh[4], fbl[4];
        #pragma unroll
        for (int mt = 0; mt < 2; ++mt) {
            fah[mt] = *reinterpret_cast<const s16x8*>(&Ah[q][w * 32 + mt * 16 + m][0]);
            fal[mt] = *reinterpret_cast<const s16x8*>(&Al[q][w * 32 + mt * 16 + m][0]);
        }
        #pragma unroll
        for (int nt = 0; nt < 4; ++nt) {
            fbh[nt] = *reinterpret_cast<const s16x8*>(&Bh[q][nt * 16 + m][0]);
            fbl[nt] = *reinterpret_cast<const s16x8*>(&Bl[q][nt * 16 + m][0]);
        }
        #pragma unroll
        for (int mt = 0; mt < 2; ++mt)
            #pragma unroll
            for (int nt = 0; nt < 4; ++nt) {
                acc[mt][nt] = __builtin_amdgcn_mfma_f32_16x16x32_bf16(fah[mt], fbh[nt], acc[mt][nt], 0, 0, 0);
                acc[mt][nt] = __builtin_amdgcn_mfma_f32_16x16x32_bf16(fah[mt], fbl[nt], acc[mt][nt], 0, 0, 0);
                acc[mt][nt] = __builtin_amdgcn_mfma_f32_16x16x32_bf16(fal[mt], fbh[nt], acc[mt][nt], 0, 0, 0);
            }
    }

    #pragma unroll
    for (int mt = 0; mt < 2; ++mt) {
        #pragma unroll
        for (int nt = 0; nt < 4; ++nt) {
            #pragma unroll
            for (int r = 0; r < 4; ++r) {
                const int lr = w * 32 + mt * 16 + q * 4 + r;
                const int lc = nt * 16 + m;
                const float d2 = sqA[lr] + sqB[lc] - 2.0f * acc[mt][nt][r];
                distp[(size_t)(row0 + lr) * NN + col0 + lc] = (d2 > 0.f) ? sqrtf(d2) : 0.f;
            }
        }
    }
}

// ---------------- kernel 3: per-row double-space scans + window lookup ------
// first idx in [lo,hi) with key[idx] >= d (right segment: keys non-decreasing)
__device__ __forceinline__ int bs_right(const float* key, float d, int lo, int hi) {
    while (lo < hi) {
        const int mid = (lo + hi) >> 1;
        if (key[mid] >= d) hi = mid; else lo = mid + 1;
    }
    return lo;
}
// first idx in [lo,hi) with key[idx] < d (left segment: keys non-increasing)
__device__ __forceinline__ int bs_left(const float* key, float d, int lo, int hi) {
    while (lo < hi) {
        const int mid = (lo + hi) >> 1;
        if (key[mid] < d) hi = mid; else lo = mid + 1;
    }
    return lo;
}

__global__ __launch_bounds__(256) void row_kernel(const float* __restrict__ distp,
                                                  const float* __restrict__ labels,
                                                  const float* __restrict__ slab,
                                                  const int* __restrict__ inv,
                                                  double* __restrict__ rowval) {
    __shared__ float  key[NN];
    __shared__ double Pd[NN];       // prefix: sum_{q<p} e_q
    __shared__ double Sd[NN + 1];   // suffix: sum_{q>=p} e_q
    __shared__ float  wmx[4];
    __shared__ double wps[4], wss[4], wD[4], wL[4];

    const int i = blockIdx.x;
    const int t = threadIdx.x;
    const int lane = t & 63;
    const int w = t >> 6;
    const int pos_i = inv[i];
    const float x = labels[i & (BB - 1)];
    const float negInvT = -1.0f / 0.07f;
    const float* drow = &distp[(size_t)i * NN];

    // ---- keys (coalesced), vals (thread-own 8, registers), row max ----
    #pragma unroll
    for (int e = 0; e < 2; ++e) {
        const int p4 = t + e * NT;
        const float4 l4 = reinterpret_cast<const float4*>(slab)[p4];
        key[p4 * 4 + 0] = fabsf(l4.x - x);
        key[p4 * 4 + 1] = fabsf(l4.y - x);
        key[p4 * 4 + 2] = fabsf(l4.z - x);
        key[p4 * 4 + 3] = fabsf(l4.w - x);
    }
    const int cb = t * 8;
    float v[8];
    double dsum = 0.0;
    float mx = NEGINF;
    #pragma unroll
    for (int e = 0; e < 2; ++e) {
        const float4 d4 = reinterpret_cast<const float4*>(drow)[2 * t + e];
        const float dv[4] = {d4.x, d4.y, d4.z, d4.w};
        #pragma unroll
        for (int c = 0; c < 4; ++c) {
            const int pc = cb + e * 4 + c;
            if (pc == pos_i) {
                v[e * 4 + c] = NEGINF;
            } else {
                const float vv = dv[c] * negInvT;
                v[e * 4 + c] = vv;
                mx = fmaxf(mx, vv);
                dsum += (double)dv[c];
            }
        }
    }
    #pragma unroll
    for (int st = 32; st > 0; st >>= 1) mx = fmaxf(mx, __shfl_down(mx, st));
    if (lane == 0) wmx[w] = mx;
    __syncthreads();   // B1: keys + wave maxima ready
    const float M = fmaxf(fmaxf(wmx[0], wmx[1]), fmaxf(wmx[2], wmx[3]));

    // ---- e_q = exp(v-M) in double via squared half-exp (hw __expf) ----
    double e8[8];
    #pragma unroll
    for (int jj = 0; jj < 8; ++jj) {
        const float tt = __expf((v[jj] - M) * 0.5f);   // exp(-inf)=0 at diag
        e8[jj] = (double)tt * (double)tt;
    }

    // ---- prefix sum ----
    {
        double run = 0.0, ex[8];
        #pragma unroll
        for (int jj = 0; jj < 8; ++jj) { ex[jj] = run; run += e8[jj]; }
        double inc = run;
        #pragma unroll
        for (int st = 1; st < 64; st <<= 1) {
            const double nm = __shfl_up(inc, st);
            if (lane >= st) inc += nm;
        }
        double xofs = __shfl_up(inc, 1);
        if (lane == 0) xofs = 0.0;
        if (lane == 63) wps[w] = inc;
        __syncthreads();   // B2
        #pragma unroll
        for (int ww = 0; ww < 3; ++ww)
            if (ww < w) xofs += wps[ww];
        #pragma unroll
        for (int jj = 0; jj < 8; ++jj) Pd[cb + jj] = ex[jj] + xofs;
    }

    // ---- suffix sum ----
    {
        double run = 0.0, sx[8];
        #pragma unroll
        for (int jj = 7; jj >= 0; --jj) { run += e8[jj]; sx[jj] = run; }
        double inc = run;
        #pragma unroll
        for (int st = 1; st < 64; st <<= 1) {
            const double nm = __shfl_down(inc, st);
            if (lane + st < 64) inc += nm;
        }
        double xofs = __shfl_down(inc, 1);
        if (lane == 63) xofs = 0.0;
        if (lane == 0) wss[w] = inc;
        __syncthreads();   // B3
        #pragma unroll
        for (int ww = 1; ww < 4; ++ww)
            if (ww > w) xofs += wss[ww];
        #pragma unroll
        for (int jj = 0; jj < 8; ++jj) Sd[cb + jj] = sx[jj] + xofs;
        if (t == 0) Sd[NN] = 0.0;
    }
    __syncthreads();   // B4: Pd/Sd ready

    // ---- windows: tie scan (same side) + bracketed search (cross side) ----
    double lnsum = 0.0;
    const int a = cb, b = cb + 7;
    {
        const int le = (pos_i - 1 < b) ? pos_i - 1 : b;
        if (a <= le) {
            const float da = key[a];
            const int Ra = bs_right(key, da, pos_i, NN);
            int Rl = Ra;
            if (le > a) Rl = bs_right(key, key[le], pos_i, Ra);
            for (int p = a; p <= le; ++p) {
                const float d = key[p];
                int R;
                if (p == a) R = Ra;
                else if (p == le) R = Rl;
                else R = bs_right(key, d, Rl, Ra);
                int L = p + 1;
                while (L < pos_i && key[L] == d) ++L;
                lnsum += (double)(M + dlogf(Pd[L] + Sd[R]));
            }
        }
    }
    {
        const int rs = (pos_i + 1 > a) ? pos_i + 1 : a;
        if (rs <= b) {
            const float dr = key[rs];
            const int Lr = bs_left(key, dr, 0, pos_i);
            int Lb = Lr;
            if (b > rs) Lb = bs_left(key, key[b], 0, Lr);
            for (int p = rs; p <= b; ++p) {
                const float d = key[p];
                int L;
                if (p == rs) L = Lr;
                else if (p == b) L = Lb;
                else L = bs_left(key, d, Lb, Lr);
                int R = p;
                while (R > pos_i && key[R - 1] == d) --R;
                lnsum += (double)(M + dlogf(Pd[L] + Sd[R]));
            }
        }
    }

    #pragma unroll
    for (int st = 32; st > 0; st >>= 1) {
        dsum  += __shfl_down(dsum, st);
        lnsum += __shfl_down(lnsum, st);
    }
    if (lane == 0) { wD[w] = dsum; wL[w] = lnsum; }
    __syncthreads();   // B5
    if (t == 0) {
        const double td = wD[0] + wD[1] + wD[2] + wD[3];
        const double tl = wL[0] + wL[1] + wL[2] + wL[3];
        rowval[i] = (-td / 0.07) - tl;
    }
}

// ---------------- kernel 4: final mean ----------------
__global__ __launch_bounds__(256) void finalize_kernel(const double* __restrict__ rowval,
                                                       float* __restrict__ out) {
    __shared__ double red[NT];
    const int t = threadIdx.x;
    double s = 0.0;
    for (int j = t; j < NN; j += NT) s += rowval[j];
    red[t] = s;
    __syncthreads();
    for (int ofs = NT / 2; ofs > 0; ofs >>= 1) {
        if (t < ofs) red[t] += red[t + ofs];
        __syncthreads();
    }
    if (t == 0) {
        out[0] = (float)(-red[0] / ((double)NN * (double)(NN - 1)));
    }
}

extern "C" void kernel_launch(void* const* d_in, const int* in_sizes, int n_in,
                              void* d_out, int out_size, void* d_ws, size_t ws_size,
                              hipStream_t stream) {
    const float* features = (const float*)d_in[0];  // [1024, 2, 512] fp32
    const float* labels   = (const float*)d_in[1];  // [1024] fp32
    float* out = (float*)d_out;

    char* ws = (char*)d_ws;
    size_t off = 0;
    float*  sq     = (float*) (ws + off); off += NN * sizeof(float);
    float*  slab   = (float*) (ws + off); off += NN * sizeof(float);
    int*    sj     = (int*)   (ws + off); off += NN * sizeof(int);
    int*    inv    = (int*)   (ws + off); off += NN * sizeof(int);
    double* rowval = (double*)(ws + off); off += NN * sizeof(double);
    ushort* Ahi    = (ushort*)(ws + off); off += (size_t)NN * DD * sizeof(ushort);
    ushort* Alo    = (ushort*)(ws + off); off += (size_t)NN * DD * sizeof(ushort);
    float*  distp  = (float*) (ws + off); off += (size_t)NN * NN * sizeof(float);

    sort_labels_kernel<<<1, 512, 0, stream>>>(labels, slab, sj, inv);
    prep_split_kernel<<<NN / 4, NT, 0, stream>>>(features, Ahi, Alo, sq);
    dim3 ggrid(NN / TN, NN / TM);
    gemm_dist_kernel<<<ggrid, NT, 0, stream>>>(Ahi, Alo, sq, sj, distp);
    row_kernel<<<NN, NT, 0, stream>>>(distp, labels, slab, inv, rowval);
    finalize_kernel<<<1, NT, 0, stream>>>(rowval, out);
}

// Round 7
// 142.626 us; speedup vs baseline: 2.4994x; 1.1312x over previous
//
#include <hip/hip_runtime.h>
#include <math.h>

// SupCR loss, MI355X. Round 7:
//  - row_kernel: fp32 scans with exponent pre-scale (+64 logit bias), LDS
//    41.5->24.7 KB => 6 blocks/CU; lookup = M-64+__logf(P[L]+S[R]).
//  - GEMM A-side also permuted: distp is the symmetric label-sorted matrix,
//    row_kernel indexes by sorted position (no inv).
//  - sort_labels: barriers only for cross-wave passes (j>=32), 55->15.
// GEMM core (3-term bf16-split MFMA, 128x64 tile) unchanged.

#define NN 2048      // N = B*V
#define BB 1024      // B
#define DD 512       // D
#define NT 256       // threads per block
#define NEGINF (-INFINITY)
#define CS 64.0f     // exponent pre-scale bias

typedef short s16x8 __attribute__((ext_vector_type(8)));
typedef float f32x4 __attribute__((ext_vector_type(4)));

// row i of the virtual cf matrix lives at F + ((i%B)*2 + i/B)*D
__device__ __forceinline__ const float* cf_row(const float* F, int i) {
    return F + ((size_t)(i & (BB - 1)) * 2 + (size_t)(i >> 10)) * DD;
}

__device__ __forceinline__ unsigned bf_rne(float x) {
    const unsigned u = __float_as_uint(x);
    return (u + 0x7FFFu + ((u >> 16) & 1u)) >> 16;
}
__device__ __forceinline__ float bf_val(unsigned h) {
    return __uint_as_float(h << 16);
}

// ---------------- kernel 0: sort labels once (512 thr) ----------------
__global__ __launch_bounds__(512) void sort_labels_kernel(const float* __restrict__ labels,
                                                          float* __restrict__ slab,
                                                          int* __restrict__ sj) {
    __shared__ float kk[BB];
    __shared__ int   id[BB];
    const int t = threadIdx.x;
    #pragma unroll
    for (int e = 0; e < 2; ++e) { const int p = t + e * 512; kk[p] = labels[p]; id[p] = p; }
    for (int k = 2; k <= BB; k <<= 1) {
        for (int j = k >> 1; j > 0; j >>= 1) {
            // cross-wave exchange only when j>=32 (pairs span a 64-lane block,
            // or previous pass wrote cross-wave); j<32 stays wave-local.
            if (j >= 32) __syncthreads();
            else __builtin_amdgcn_wave_barrier();
            #pragma unroll
            for (int e = 0; e < 2; ++e) {
                const int idx = t + e * 512;
                const int ixj = idx ^ j;
                if (ixj > idx) {
                    const float k1 = kk[idx], k2 = kk[ixj];
                    const bool up = ((idx & k) == 0);
                    if (up ? (k1 > k2) : (k1 < k2)) {
                        kk[idx] = k2; kk[ixj] = k1;
                        const int i1 = id[idx]; id[idx] = id[ixj]; id[ixj] = i1;
                    }
                }
            }
        }
    }
    __syncthreads();
    #pragma unroll
    for (int e = 0; e < 2; ++e) {
        const int p = t + e * 512;
        const float lv = kk[p];
        const int b = id[p];
        slab[2 * p] = lv; slab[2 * p + 1] = lv;
        sj[2 * p] = b;    sj[2 * p + 1] = b + BB;
    }
}

// ---------------- kernel 1: bf16 hi/lo split + squared norms ----------------
__global__ __launch_bounds__(256) void prep_split_kernel(const float* __restrict__ F,
                                                         ushort* __restrict__ Ahi,
                                                         ushort* __restrict__ Alo,
                                                         float* __restrict__ sq) {
    const int t = threadIdx.x;
    const int lane = t & 63;
    const int w = t >> 6;
    const int i = blockIdx.x * 4 + w;
    const float* src = cf_row(F, i);
    const float4 v0 = reinterpret_cast<const float4*>(src)[lane];
    const float4 v1 = reinterpret_cast<const float4*>(src)[lane + 64];
    float ss = v0.x * v0.x + v0.y * v0.y + v0.z * v0.z + v0.w * v0.w
             + v1.x * v1.x + v1.y * v1.y + v1.z * v1.z + v1.w * v1.w;
    #pragma unroll
    for (int st = 32; st > 0; st >>= 1) ss += __shfl_down(ss, st);
    if (lane == 0) sq[i] = ss;

    const float a[8] = {v0.x, v0.y, v0.z, v0.w, v1.x, v1.y, v1.z, v1.w};
    ushort h[8], l[8];
    #pragma unroll
    for (int e = 0; e < 8; ++e) {
        const unsigned hb = bf_rne(a[e]);
        h[e] = (ushort)hb;
        l[e] = (ushort)bf_rne(a[e] - bf_val(hb));
    }
    const size_t base = (size_t)i * DD;
    *reinterpret_cast<ushort4*>(&Ahi[base + lane * 4])       = make_ushort4(h[0], h[1], h[2], h[3]);
    *reinterpret_cast<ushort4*>(&Ahi[base + 256 + lane * 4]) = make_ushort4(h[4], h[5], h[6], h[7]);
    *reinterpret_cast<ushort4*>(&Alo[base + lane * 4])       = make_ushort4(l[0], l[1], l[2], l[3]);
    *reinterpret_cast<ushort4*>(&Alo[base + 256 + lane * 4]) = make_ushort4(l[4], l[5], l[6], l[7]);
}

// ---------------- kernel 2: MFMA dist, 128x64 tile, both sides permuted -----
#define TM 128
#define TN 64
#define TK 32
__global__ __launch_bounds__(256) void gemm_dist_kernel(const ushort* __restrict__ Ahi,
                                                        const ushort* __restrict__ Alo,
                                                        const float* __restrict__ sq,
                                                        const int* __restrict__ sj,
                                                        float* __restrict__ distp) {
    __shared__ ushort Ah[4][TM][8];
    __shared__ ushort Al[4][TM][8];
    __shared__ ushort Bh[4][TN][8];
    __shared__ ushort Bl[4][TN][8];
    __shared__ int   sjcA[TM];
    __shared__ int   sjcB[TN];
    __shared__ float sqA[TM];
    __shared__ float sqB[TN];

    const int t = threadIdx.x;
    const int lane = t & 63;
    const int w = t >> 6;
    const int row0 = blockIdx.y * TM;
    const int col0 = blockIdx.x * TN;

    if (t < TM) {
        const int s = sj[row0 + t];
        sjcA[t] = s; sqA[t] = sq[s];
    } else if (t < TM + TN) {
        const int u = t - TM;
        const int s = sj[col0 + u];
        sjcB[u] = s; sqB[u] = sq[s];
    }
    __syncthreads();
    // each thread stages rows rA0, rA1 (A) and rB0 (B) at chunk cq
    const int rr = t >> 2;
    const int cq = t & 3;
    const size_t gA0 = (size_t)sjcA[rr] * DD + cq * 8;
    const size_t gA1 = (size_t)sjcA[64 + rr] * DD + cq * 8;
    const size_t gB0 = (size_t)sjcB[rr] * DD + cq * 8;

    f32x4 acc[2][4] = {};
    const int m = lane & 15;
    const int q = lane >> 4;

    for (int kt = 0; kt < DD / TK; ++kt) {
        __syncthreads();
        const size_t ko = (size_t)kt * TK;
        *reinterpret_cast<int4*>(&Ah[cq][rr][0])      = *reinterpret_cast<const int4*>(&Ahi[gA0 + ko]);
        *reinterpret_cast<int4*>(&Al[cq][rr][0])      = *reinterpret_cast<const int4*>(&Alo[gA0 + ko]);
        *reinterpret_cast<int4*>(&Ah[cq][64 + rr][0]) = *reinterpret_cast<const int4*>(&Ahi[gA1 + ko]);
        *reinterpret_cast<int4*>(&Al[cq][64 + rr][0]) = *reinterpret_cast<const int4*>(&Alo[gA1 + ko]);
        *reinterpret_cast<int4*>(&Bh[cq][rr][0])      = *reinterpret_cast<const int4*>(&Ahi[gB0 + ko]);
        *reinterpret_cast<int4*>(&Bl[cq][rr][0])      = *reinterpret_cast<const int4*>(&Alo[gB0 + ko]);
        __syncthreads();

        s16x8 fah[2], fal[2], fbh[4], fbl[4];
        #pragma unroll
        for (int mt = 0; mt < 2; ++mt) {
            fah[mt] = *reinterpret_cast<const s16x8*>(&Ah[q][w * 32 + mt * 16 + m][0]);
            fal[mt] = *reinterpret_cast<const s16x8*>(&Al[q][w * 32 + mt * 16 + m][0]);
        }
        #pragma unroll
        for (int nt = 0; nt < 4; ++nt) {
            fbh[nt] = *reinterpret_cast<const s16x8*>(&Bh[q][nt * 16 + m][0]);
            fbl[nt] = *reinterpret_cast<const s16x8*>(&Bl[q][nt * 16 + m][0]);
        }
        #pragma unroll
        for (int mt = 0; mt < 2; ++mt)
            #pragma unroll
            for (int nt = 0; nt < 4; ++nt) {
                acc[mt][nt] = __builtin_amdgcn_mfma_f32_16x16x32_bf16(fah[mt], fbh[nt], acc[mt][nt], 0, 0, 0);
                acc[mt][nt] = __builtin_amdgcn_mfma_f32_16x16x32_bf16(fah[mt], fbl[nt], acc[mt][nt], 0, 0, 0);
                acc[mt][nt] = __builtin_amdgcn_mfma_f32_16x16x32_bf16(fal[mt], fbh[nt], acc[mt][nt], 0, 0, 0);
            }
    }

    #pragma unroll
    for (int mt = 0; mt < 2; ++mt) {
        #pragma unroll
        for (int nt = 0; nt < 4; ++nt) {
            #pragma unroll
            for (int r = 0; r < 4; ++r) {
                const int lr = w * 32 + mt * 16 + q * 4 + r;
                const int lc = nt * 16 + m;
                const float d2 = sqA[lr] + sqB[lc] - 2.0f * acc[mt][nt][r];
                distp[(size_t)(row0 + lr) * NN + col0 + lc] = (d2 > 0.f) ? sqrtf(d2) : 0.f;
            }
        }
    }
}

// ---------------- kernel 3: per-row fp32 scans + window lookup ----------------
// first idx in [lo,hi) with key[idx] >= d (right segment: keys non-decreasing)
__device__ __forceinline__ int bs_right(const float* key, float d, int lo, int hi) {
    while (lo < hi) {
        const int mid = (lo + hi) >> 1;
        if (key[mid] >= d) hi = mid; else lo = mid + 1;
    }
    return lo;
}
// first idx in [lo,hi) with key[idx] < d (left segment: keys non-increasing)
__device__ __forceinline__ int bs_left(const float* key, float d, int lo, int hi) {
    while (lo < hi) {
        const int mid = (lo + hi) >> 1;
        if (key[mid] < d) hi = mid; else lo = mid + 1;
    }
    return lo;
}

__global__ __launch_bounds__(256) void row_kernel(const float* __restrict__ distp,
                                                  const float* __restrict__ slab,
                                                  double* __restrict__ rowval) {
    __shared__ float key[NN];
    __shared__ float Pf[NN];       // prefix: sum_{q<p} e_q   (scaled by e^CS)
    __shared__ float Sf[NN + 1];   // suffix: sum_{q>=p} e_q  (scaled by e^CS)
    __shared__ float wmx[4], wps[4], wss[4];
    __shared__ double wD[4], wL[4];

    const int r = blockIdx.x;            // sorted position
    const int t = threadIdx.x;
    const int lane = t & 63;
    const int w = t >> 6;
    const float x = slab[r];
    const float negInvT = -1.0f / 0.07f;
    const float* drow = &distp[(size_t)r * NN];

    // ---- keys (coalesced), vals (thread-own 8, registers), row max ----
    #pragma unroll
    for (int e = 0; e < 2; ++e) {
        const int p4 = t + e * NT;
        const float4 l4 = reinterpret_cast<const float4*>(slab)[p4];
        key[p4 * 4 + 0] = fabsf(l4.x - x);
        key[p4 * 4 + 1] = fabsf(l4.y - x);
        key[p4 * 4 + 2] = fabsf(l4.z - x);
        key[p4 * 4 + 3] = fabsf(l4.w - x);
    }
    const int cb = t * 8;
    float v[8];
    double dsum = 0.0;
    float mx = NEGINF;
    #pragma unroll
    for (int e = 0; e < 2; ++e) {
        const float4 d4 = reinterpret_cast<const float4*>(drow)[2 * t + e];
        const float dv[4] = {d4.x, d4.y, d4.z, d4.w};
        #pragma unroll
        for (int c = 0; c < 4; ++c) {
            const int pc = cb + e * 4 + c;
            if (pc == r) {
                v[e * 4 + c] = NEGINF;
            } else {
                const float vv = dv[c] * negInvT;
                v[e * 4 + c] = vv;
                mx = fmaxf(mx, vv);
                dsum += (double)dv[c];
            }
        }
    }
    #pragma unroll
    for (int st = 32; st > 0; st >>= 1) mx = fmaxf(mx, __shfl_down(mx, st));
    if (lane == 0) wmx[w] = mx;
    __syncthreads();   // B1: keys + wave maxima ready
    const float M = fmaxf(fmaxf(wmx[0], wmx[1]), fmaxf(wmx[2], wmx[3]));

    // ---- e_q = exp(v - M + CS), fp32 (range-safe via +CS bias) ----
    float e8[8];
    #pragma unroll
    for (int jj = 0; jj < 8; ++jj) e8[jj] = __expf(v[jj] - M + CS);  // diag -> 0

    // ---- prefix sum (fp32) ----
    {
        float run = 0.f, ex[8];
        #pragma unroll
        for (int jj = 0; jj < 8; ++jj) { ex[jj] = run; run += e8[jj]; }
        float inc = run;
        #pragma unroll
        for (int st = 1; st < 64; st <<= 1) {
            const float nm = __shfl_up(inc, st);
            if (lane >= st) inc += nm;
        }
        float xofs = __shfl_up(inc, 1);
        if (lane == 0) xofs = 0.f;
        if (lane == 63) wps[w] = inc;
        __syncthreads();   // B2
        #pragma unroll
        for (int ww = 0; ww < 3; ++ww)
            if (ww < w) xofs += wps[ww];
        #pragma unroll
        for (int jj = 0; jj < 8; ++jj) Pf[cb + jj] = ex[jj] + xofs;
    }

    // ---- suffix sum (fp32) ----
    {
        float run = 0.f, sx[8];
        #pragma unroll
        for (int jj = 7; jj >= 0; --jj) { run += e8[jj]; sx[jj] = run; }
        float inc = run;
        #pragma unroll
        for (int st = 1; st < 64; st <<= 1) {
            const float nm = __shfl_down(inc, st);
            if (lane + st < 64) inc += nm;
        }
        float xofs = __shfl_down(inc, 1);
        if (lane == 63) xofs = 0.f;
        if (lane == 0) wss[w] = inc;
        __syncthreads();   // B3
        #pragma unroll
        for (int ww = 1; ww < 4; ++ww)
            if (ww > w) xofs += wss[ww];
        #pragma unroll
        for (int jj = 0; jj < 8; ++jj) Sf[cb + jj] = sx[jj] + xofs;
        if (t == 0) Sf[NN] = 0.f;
    }
    __syncthreads();   // B4: Pf/Sf ready

    // ---- windows: tie scan (same side) + bracketed search (cross side) ----
    double lnsum = 0.0;
    const int a = cb, b = cb + 7;
    const float MB = M - CS;
    {
        const int le = (r - 1 < b) ? r - 1 : b;
        if (a <= le) {
            const float da = key[a];
            const int Ra = bs_right(key, da, r, NN);
            int Rl = Ra;
            if (le > a) Rl = bs_right(key, key[le], r, Ra);
            for (int p = a; p <= le; ++p) {
                const float d = key[p];
                int R;
                if (p == a) R = Ra;
                else if (p == le) R = Rl;
                else R = bs_right(key, d, Rl, Ra);
                int L = p + 1;
                while (L < r && key[L] == d) ++L;
                const float s = fmaxf(Pf[L] + Sf[R], 1e-38f);
                lnsum += (double)(MB + __logf(s));
            }
        }
    }
    {
        const int rs = (r + 1 > a) ? r + 1 : a;
        if (rs <= b) {
            const float dr = key[rs];
            const int Lr = bs_left(key, dr, 0, r);
            int Lb = Lr;
            if (b > rs) Lb = bs_left(key, key[b], 0, Lr);
            for (int p = rs; p <= b; ++p) {
                const float d = key[p];
                int L;
                if (p == rs) L = Lr;
                else if (p == b) L = Lb;
                else L = bs_left(key, d, Lb, Lr);
                int R = p;
                while (R > r && key[R - 1] == d) --R;
                const float s = fmaxf(Pf[L] + Sf[R], 1e-38f);
                lnsum += (double)(MB + __logf(s));
            }
        }
    }

    #pragma unroll
    for (int st = 32; st > 0; st >>= 1) {
        dsum  += __shfl_down(dsum, st);
        lnsum += __shfl_down(lnsum, st);
    }
    if (lane == 0) { wD[w] = dsum; wL[w] = lnsum; }
    __syncthreads();   // B5
    if (t == 0) {
        const double td = wD[0] + wD[1] + wD[2] + wD[3];
        const double tl = wL[0] + wL[1] + wL[2] + wL[3];
        rowval[r] = (-td / 0.07) - tl;
    }
}

// ---------------- kernel 4: final mean ----------------
__global__ __launch_bounds__(256) void finalize_kernel(const double* __restrict__ rowval,
                                                       float* __restrict__ out) {
    __shared__ double red[NT];
    const int t = threadIdx.x;
    double s = 0.0;
    for (int j = t; j < NN; j += NT) s += rowval[j];
    red[t] = s;
    __syncthreads();
    for (int ofs = NT / 2; ofs > 0; ofs >>= 1) {
        if (t < ofs) red[t] += red[t + ofs];
        __syncthreads();
    }
    if (t == 0) {
        out[0] = (float)(-red[0] / ((double)NN * (double)(NN - 1)));
    }
}

extern "C" void kernel_launch(void* const* d_in, const int* in_sizes, int n_in,
                              void* d_out, int out_size, void* d_ws, size_t ws_size,
                              hipStream_t stream) {
    const float* features = (const float*)d_in[0];  // [1024, 2, 512] fp32
    const float* labels   = (const float*)d_in[1];  // [1024] fp32
    float* out = (float*)d_out;

    char* ws = (char*)d_ws;
    size_t off = 0;
    float*  sq     = (float*) (ws + off); off += NN * sizeof(float);
    float*  slab   = (float*) (ws + off); off += NN * sizeof(float);
    int*    sj     = (int*)   (ws + off); off += NN * sizeof(int);
    double* rowval = (double*)(ws + off); off += NN * sizeof(double);
    ushort* Ahi    = (ushort*)(ws + off); off += (size_t)NN * DD * sizeof(ushort);
    ushort* Alo    = (ushort*)(ws + off); off += (size_t)NN * DD * sizeof(ushort);
    float*  distp  = (float*) (ws + off); off += (size_t)NN * NN * sizeof(float);

    sort_labels_kernel<<<1, 512, 0, stream>>>(labels, slab, sj);
    prep_split_kernel<<<NN / 4, NT, 0, stream>>>(features, Ahi, Alo, sq);
    dim3 ggrid(NN / TN, NN / TM);
    gemm_dist_kernel<<<ggrid, NT, 0, stream>>>(Ahi, Alo, sq, sj, distp);
    row_kernel<<<NN, NT, 0, stream>>>(distp, slab, rowval);
    finalize_kernel<<<1, NT, 0, stream>>>(rowval, out);
}

// Round 8
// 134.185 us; speedup vs baseline: 2.6566x; 1.0629x over previous
//
#include <hip/hip_runtime.h>
#include <math.h>

// SupCR loss, MI355X. Round 8:
//  - GEMM: dist matrix (both sides label-sorted) is symmetric -> enumerate
//    only the 272/512 tiles on/below the diagonal band; below-diag tiles
//    also emit their transpose (float4 along r => coalesced 64B segments).
//  - row_kernel: rows 2p,2p+1 share a label => identical key[] and identical
//    per-element windows [L,R). One block does both rows: searches ONCE
//    (L/R in regs), scans per row reusing Pf/Sf LDS. 1024 blocks.
// Math identical to round 7 (fp32 scans with +64 exponent bias).

#define NN 2048      // N = B*V
#define BB 1024      // B
#define DD 512       // D
#define NT 256       // threads per block
#define NEGINF (-INFINITY)
#define CS 64.0f     // exponent pre-scale bias

typedef short s16x8 __attribute__((ext_vector_type(8)));
typedef float f32x4 __attribute__((ext_vector_type(4)));

// row i of the virtual cf matrix lives at F + ((i%B)*2 + i/B)*D
__device__ __forceinline__ const float* cf_row(const float* F, int i) {
    return F + ((size_t)(i & (BB - 1)) * 2 + (size_t)(i >> 10)) * DD;
}

__device__ __forceinline__ unsigned bf_rne(float x) {
    const unsigned u = __float_as_uint(x);
    return (u + 0x7FFFu + ((u >> 16) & 1u)) >> 16;
}
__device__ __forceinline__ float bf_val(unsigned h) {
    return __uint_as_float(h << 16);
}

// ---------------- kernel 0: sort labels once (512 thr) ----------------
__global__ __launch_bounds__(512) void sort_labels_kernel(const float* __restrict__ labels,
                                                          float* __restrict__ slab,
                                                          int* __restrict__ sj) {
    __shared__ float kk[BB];
    __shared__ int   id[BB];
    const int t = threadIdx.x;
    #pragma unroll
    for (int e = 0; e < 2; ++e) { const int p = t + e * 512; kk[p] = labels[p]; id[p] = p; }
    for (int k = 2; k <= BB; k <<= 1) {
        for (int j = k >> 1; j > 0; j >>= 1) {
            if (j >= 32) __syncthreads();
            else __builtin_amdgcn_wave_barrier();
            #pragma unroll
            for (int e = 0; e < 2; ++e) {
                const int idx = t + e * 512;
                const int ixj = idx ^ j;
                if (ixj > idx) {
                    const float k1 = kk[idx], k2 = kk[ixj];
                    const bool up = ((idx & k) == 0);
                    if (up ? (k1 > k2) : (k1 < k2)) {
                        kk[idx] = k2; kk[ixj] = k1;
                        const int i1 = id[idx]; id[idx] = id[ixj]; id[ixj] = i1;
                    }
                }
            }
        }
    }
    __syncthreads();
    #pragma unroll
    for (int e = 0; e < 2; ++e) {
        const int p = t + e * 512;
        const float lv = kk[p];
        const int b = id[p];
        slab[2 * p] = lv; slab[2 * p + 1] = lv;
        sj[2 * p] = b;    sj[2 * p + 1] = b + BB;
    }
}

// ---------------- kernel 1: bf16 hi/lo split + squared norms ----------------
__global__ __launch_bounds__(256) void prep_split_kernel(const float* __restrict__ F,
                                                         ushort* __restrict__ Ahi,
                                                         ushort* __restrict__ Alo,
                                                         float* __restrict__ sq) {
    const int t = threadIdx.x;
    const int lane = t & 63;
    const int w = t >> 6;
    const int i = blockIdx.x * 4 + w;
    const float* src = cf_row(F, i);
    const float4 v0 = reinterpret_cast<const float4*>(src)[lane];
    const float4 v1 = reinterpret_cast<const float4*>(src)[lane + 64];
    float ss = v0.x * v0.x + v0.y * v0.y + v0.z * v0.z + v0.w * v0.w
             + v1.x * v1.x + v1.y * v1.y + v1.z * v1.z + v1.w * v1.w;
    #pragma unroll
    for (int st = 32; st > 0; st >>= 1) ss += __shfl_down(ss, st);
    if (lane == 0) sq[i] = ss;

    const float a[8] = {v0.x, v0.y, v0.z, v0.w, v1.x, v1.y, v1.z, v1.w};
    ushort h[8], l[8];
    #pragma unroll
    for (int e = 0; e < 8; ++e) {
        const unsigned hb = bf_rne(a[e]);
        h[e] = (ushort)hb;
        l[e] = (ushort)bf_rne(a[e] - bf_val(hb));
    }
    const size_t base = (size_t)i * DD;
    *reinterpret_cast<ushort4*>(&Ahi[base + lane * 4])       = make_ushort4(h[0], h[1], h[2], h[3]);
    *reinterpret_cast<ushort4*>(&Ahi[base + 256 + lane * 4]) = make_ushort4(h[4], h[5], h[6], h[7]);
    *reinterpret_cast<ushort4*>(&Alo[base + lane * 4])       = make_ushort4(l[0], l[1], l[2], l[3]);
    *reinterpret_cast<ushort4*>(&Alo[base + 256 + lane * 4]) = make_ushort4(l[4], l[5], l[6], l[7]);
}

// ---------------- kernel 2: MFMA dist, symmetric (lower tiles only) ---------
#define TM 128
#define TN 64
#define TK 32
__global__ __launch_bounds__(256) void gemm_dist_kernel(const ushort* __restrict__ Ahi,
                                                        const ushort* __restrict__ Alo,
                                                        const float* __restrict__ sq,
                                                        const int* __restrict__ sj,
                                                        float* __restrict__ distp) {
    __shared__ ushort Ah[4][TM][8];
    __shared__ ushort Al[4][TM][8];
    __shared__ ushort Bh[4][TN][8];
    __shared__ ushort Bl[4][TN][8];
    __shared__ int   sjcA[TM];
    __shared__ int   sjcB[TN];
    __shared__ float sqA[TM];
    __shared__ float sqB[TN];

    const int t = threadIdx.x;
    const int lane = t & 63;
    const int w = t >> 6;

    // tile id -> (by, bx) over the lower-triangular band: C(by)=by*(by+1)
    const int id = blockIdx.x;
    int by = (int)((__fsqrt_rn(4.0f * (float)id + 1.0f) - 1.0f) * 0.5f);
    while ((by + 1) * (by + 2) <= id) ++by;
    while (by * (by + 1) > id) --by;
    const int bx = id - by * (by + 1);          // 0 .. 2*by+1
    const int row0 = by * TM;
    const int col0 = bx * TN;
    const bool below = (bx < 2 * by);           // strictly left of diag square

    if (t < TM) {
        const int s = sj[row0 + t];
        sjcA[t] = s; sqA[t] = sq[s];
    } else if (t < TM + TN) {
        const int u = t - TM;
        const int s = sj[col0 + u];
        sjcB[u] = s; sqB[u] = sq[s];
    }
    __syncthreads();
    const int rr = t >> 2;
    const int cq = t & 3;
    const size_t gA0 = (size_t)sjcA[rr] * DD + cq * 8;
    const size_t gA1 = (size_t)sjcA[64 + rr] * DD + cq * 8;
    const size_t gB0 = (size_t)sjcB[rr] * DD + cq * 8;

    f32x4 acc[2][4] = {};
    const int m = lane & 15;
    const int q = lane >> 4;

    for (int kt = 0; kt < DD / TK; ++kt) {
        __syncthreads();
        const size_t ko = (size_t)kt * TK;
        *reinterpret_cast<int4*>(&Ah[cq][rr][0])      = *reinterpret_cast<const int4*>(&Ahi[gA0 + ko]);
        *reinterpret_cast<int4*>(&Al[cq][rr][0])      = *reinterpret_cast<const int4*>(&Alo[gA0 + ko]);
        *reinterpret_cast<int4*>(&Ah[cq][64 + rr][0]) = *reinterpret_cast<const int4*>(&Ahi[gA1 + ko]);
        *reinterpret_cast<int4*>(&Al[cq][64 + rr][0]) = *reinterpret_cast<const int4*>(&Alo[gA1 + ko]);
        *reinterpret_cast<int4*>(&Bh[cq][rr][0])      = *reinterpret_cast<const int4*>(&Ahi[gB0 + ko]);
        *reinterpret_cast<int4*>(&Bl[cq][rr][0])      = *reinterpret_cast<const int4*>(&Alo[gB0 + ko]);
        __syncthreads();

        s16x8 fah[2], fal[2], fbh[4], fbl[4];
        #pragma unroll
        for (int mt = 0; mt < 2; ++mt) {
            fah[mt] = *reinterpret_cast<const s16x8*>(&Ah[q][w * 32 + mt * 16 + m][0]);
            fal[mt] = *reinterpret_cast<const s16x8*>(&Al[q][w * 32 + mt * 16 + m][0]);
        }
        #pragma unroll
        for (int nt = 0; nt < 4; ++nt) {
            fbh[nt] = *reinterpret_cast<const s16x8*>(&Bh[q][nt * 16 + m][0]);
            fbl[nt] = *reinterpret_cast<const s16x8*>(&Bl[q][nt * 16 + m][0]);
        }
        #pragma unroll
        for (int mt = 0; mt < 2; ++mt)
            #pragma unroll
            for (int nt = 0; nt < 4; ++nt) {
                acc[mt][nt] = __builtin_amdgcn_mfma_f32_16x16x32_bf16(fah[mt], fbh[nt], acc[mt][nt], 0, 0, 0);
                acc[mt][nt] = __builtin_amdgcn_mfma_f32_16x16x32_bf16(fah[mt], fbl[nt], acc[mt][nt], 0, 0, 0);
                acc[mt][nt] = __builtin_amdgcn_mfma_f32_16x16x32_bf16(fal[mt], fbh[nt], acc[mt][nt], 0, 0, 0);
            }
    }

    #pragma unroll
    for (int mt = 0; mt < 2; ++mt) {
        const int lr0 = w * 32 + mt * 16 + q * 4;
        #pragma unroll
        for (int nt = 0; nt < 4; ++nt) {
            const int lc = nt * 16 + m;
            float o[4];
            #pragma unroll
            for (int r = 0; r < 4; ++r) {
                const float d2 = sqA[lr0 + r] + sqB[lc] - 2.0f * acc[mt][nt][r];
                o[r] = (d2 > 0.f) ? sqrtf(d2) : 0.f;
            }
            #pragma unroll
            for (int r = 0; r < 4; ++r)
                distp[(size_t)(row0 + lr0 + r) * NN + col0 + lc] = o[r];
            if (below) {
                const float4 o4 = make_float4(o[0], o[1], o[2], o[3]);
                *reinterpret_cast<float4*>(&distp[(size_t)(col0 + lc) * NN + row0 + lr0]) = o4;
            }
        }
    }
}

// ---------------- kernel 3: row-pair scans + shared window lookup ----------
// first idx in [lo,hi) with key[idx] >= d (right segment: keys non-decreasing)
__device__ __forceinline__ int bs_right(const float* key, float d, int lo, int hi) {
    while (lo < hi) {
        const int mid = (lo + hi) >> 1;
        if (key[mid] >= d) hi = mid; else lo = mid + 1;
    }
    return lo;
}
// first idx in [lo,hi) with key[idx] < d (left segment: keys non-increasing)
__device__ __forceinline__ int bs_left(const float* key, float d, int lo, int hi) {
    while (lo < hi) {
        const int mid = (lo + hi) >> 1;
        if (key[mid] < d) hi = mid; else lo = mid + 1;
    }
    return lo;
}

__global__ __launch_bounds__(256) void row_kernel(const float* __restrict__ distp,
                                                  const float* __restrict__ slab,
                                                  double* __restrict__ rowval) {
    __shared__ float key[NN];
    __shared__ float Pf[NN];
    __shared__ float Sf[NN + 1];
    __shared__ float wmxA[4], wmxB[4], wps[4], wss[4];
    __shared__ double wDA[4], wLA[4], wDB[4], wLB[4];

    const int pr = blockIdx.x;           // pair index
    const int rA = 2 * pr, rB = 2 * pr + 1;
    const int t = threadIdx.x;
    const int lane = t & 63;
    const int w = t >> 6;
    const float x = slab[rA];
    const float negInvT = -1.0f / 0.07f;
    const float* drowA = &distp[(size_t)rA * NN];
    const float* drowB = &distp[(size_t)rB * NN];

    // ---- keys (shared by both rows), vals for both rows, row maxima ----
    #pragma unroll
    for (int e = 0; e < 2; ++e) {
        const int p4 = t + e * NT;
        const float4 l4 = reinterpret_cast<const float4*>(slab)[p4];
        key[p4 * 4 + 0] = fabsf(l4.x - x);
        key[p4 * 4 + 1] = fabsf(l4.y - x);
        key[p4 * 4 + 2] = fabsf(l4.z - x);
        key[p4 * 4 + 3] = fabsf(l4.w - x);
    }
    const int cb = t * 8;
    float vA[8], vB[8];
    double dsumA = 0.0, dsumB = 0.0;
    float mxA = NEGINF, mxB = NEGINF;
    #pragma unroll
    for (int e = 0; e < 2; ++e) {
        const float4 a4 = reinterpret_cast<const float4*>(drowA)[2 * t + e];
        const float4 b4 = reinterpret_cast<const float4*>(drowB)[2 * t + e];
        const float av[4] = {a4.x, a4.y, a4.z, a4.w};
        const float bv[4] = {b4.x, b4.y, b4.z, b4.w};
        #pragma unroll
        for (int c = 0; c < 4; ++c) {
            const int pc = cb + e * 4 + c;
            if (pc == rA) vA[e * 4 + c] = NEGINF;
            else { const float vv = av[c] * negInvT; vA[e * 4 + c] = vv; mxA = fmaxf(mxA, vv); dsumA += (double)av[c]; }
            if (pc == rB) vB[e * 4 + c] = NEGINF;
            else { const float vv = bv[c] * negInvT; vB[e * 4 + c] = vv; mxB = fmaxf(mxB, vv); dsumB += (double)bv[c]; }
        }
    }
    #pragma unroll
    for (int st = 32; st > 0; st >>= 1) {
        mxA = fmaxf(mxA, __shfl_down(mxA, st));
        mxB = fmaxf(mxB, __shfl_down(mxB, st));
    }
    if (lane == 0) { wmxA[w] = mxA; wmxB[w] = mxB; }
    __syncthreads();   // B1: keys + wave maxima ready
    const float MA = fmaxf(fmaxf(wmxA[0], wmxA[1]), fmaxf(wmxA[2], wmxA[3]));
    const float MB = fmaxf(fmaxf(wmxB[0], wmxB[1]), fmaxf(wmxB[2], wmxB[3]));

    // ---- window boundaries ONCE (key-determined, shared by both rows) ----
    int L8[8], R8[8];
    const int a = cb, b = cb + 7;
    {
        const int le = (rA - 1 < b) ? rA - 1 : b;
        if (a <= le) {
            const float da = key[a];
            const int Ra = bs_right(key, da, rA, NN);
            int Rl = Ra;
            if (le > a) Rl = bs_right(key, key[le], rA, Ra);
            for (int p = a; p <= le; ++p) {
                const float d = key[p];
                int R;
                if (p == a) R = Ra;
                else if (p == le) R = Rl;
                else R = bs_right(key, d, Rl, Ra);
                int L = p + 1;
                while (L < rA && key[L] == d) ++L;
                L8[p - a] = L; R8[p - a] = R;
            }
        }
        const int rs = (rA + 1 > a) ? rA + 1 : a;
        if (rs <= b) {
            const float dr = key[rs];
            const int Lr = bs_left(key, dr, 0, rA);
            int Lb = Lr;
            if (b > rs) Lb = bs_left(key, key[b], 0, Lr);
            for (int p = rs; p <= b; ++p) {
                const float d = key[p];
                int L;
                if (p == rs) L = Lr;
                else if (p == b) L = Lb;
                else L = bs_left(key, d, Lb, Lr);
                int R = p;
                while (R > rA && key[R - 1] == d) --R;
                L8[p - a] = L; R8[p - a] = R;
            }
        }
        if (rA >= a && rA <= b) { L8[rA - a] = rA; R8[rA - a] = rA; }
    }

    // ================= row A: scans + accumulate =================
    double lnsumA = 0.0;
    {
        float e8[8];
        #pragma unroll
        for (int jj = 0; jj < 8; ++jj) e8[jj] = __expf(vA[jj] - MA + CS);
        // prefix
        {
            float run = 0.f, ex[8];
            #pragma unroll
            for (int jj = 0; jj < 8; ++jj) { ex[jj] = run; run += e8[jj]; }
            float inc = run;
            #pragma unroll
            for (int st = 1; st < 64; st <<= 1) {
                const float nm = __shfl_up(inc, st);
                if (lane >= st) inc += nm;
            }
            float xofs = __shfl_up(inc, 1);
            if (lane == 0) xofs = 0.f;
            if (lane == 63) wps[w] = inc;
            __syncthreads();   // B2
            #pragma unroll
            for (int ww = 0; ww < 3; ++ww)
                if (ww < w) xofs += wps[ww];
            #pragma unroll
            for (int jj = 0; jj < 8; ++jj) Pf[cb + jj] = ex[jj] + xofs;
        }
        // suffix
        {
            float run = 0.f, sx[8];
            #pragma unroll
            for (int jj = 7; jj >= 0; --jj) { run += e8[jj]; sx[jj] = run; }
            float inc = run;
            #pragma unroll
            for (int st = 1; st < 64; st <<= 1) {
                const float nm = __shfl_down(inc, st);
                if (lane + st < 64) inc += nm;
            }
            float xofs = __shfl_down(inc, 1);
            if (lane == 63) xofs = 0.f;
            if (lane == 0) wss[w] = inc;
            __syncthreads();   // B3
            #pragma unroll
            for (int ww = 1; ww < 4; ++ww)
                if (ww > w) xofs += wss[ww];
            #pragma unroll
            for (int jj = 0; jj < 8; ++jj) Sf[cb + jj] = sx[jj] + xofs;
            if (t == 0) Sf[NN] = 0.f;
        }
        __syncthreads();   // B4: Pf/Sf(A) ready
        const float MBA = MA - CS;
        #pragma unroll
        for (int jj = 0; jj < 8; ++jj) {
            const int p = cb + jj;
            if (p == rA) continue;
            const float s = fmaxf(Pf[L8[jj]] + Sf[R8[jj]], 1e-38f);
            lnsumA += (double)(MBA + __logf(s));
        }
    }
    __syncthreads();   // B5: done reading Pf/Sf(A)

    // ================= row B: scans + accumulate =================
    double lnsumB = 0.0;
    {
        float e8[8];
        #pragma unroll
        for (int jj = 0; jj < 8; ++jj) e8[jj] = __expf(vB[jj] - MB + CS);
        {
            float run = 0.f, ex[8];
            #pragma unroll
            for (int jj = 0; jj < 8; ++jj) { ex[jj] = run; run += e8[jj]; }
            float inc = run;
            #pragma unroll
            for (int st = 1; st < 64; st <<= 1) {
                const float nm = __shfl_up(inc, st);
                if (lane >= st) inc += nm;
            }
            float xofs = __shfl_up(inc, 1);
            if (lane == 0) xofs = 0.f;
            if (lane == 63) wps[w] = inc;
            __syncthreads();   // B6
            #pragma unroll
            for (int ww = 0; ww < 3; ++ww)
                if (ww < w) xofs += wps[ww];
            #pragma unroll
            for (int jj = 0; jj < 8; ++jj) Pf[cb + jj] = ex[jj] + xofs;
        }
        {
            float run = 0.f, sx[8];
            #pragma unroll
            for (int jj = 7; jj >= 0; --jj) { run += e8[jj]; sx[jj] = run; }
            float inc = run;
            #pragma unroll
            for (int st = 1; st < 64; st <<= 1) {
                const float nm = __shfl_down(inc, st);
                if (lane + st < 64) inc += nm;
            }
            float xofs = __shfl_down(inc, 1);
            if (lane == 63) xofs = 0.f;
            if (lane == 0) wss[w] = inc;
            __syncthreads();   // B7
            #pragma unroll
            for (int ww = 1; ww < 4; ++ww)
                if (ww > w) xofs += wss[ww];
            #pragma unroll
            for (int jj = 0; jj < 8; ++jj) Sf[cb + jj] = sx[jj] + xofs;
            if (t == 0) Sf[NN] = 0.f;
        }
        __syncthreads();   // B8: Pf/Sf(B) ready
        const float MBB = MB - CS;
        #pragma unroll
        for (int jj = 0; jj < 8; ++jj) {
            const int p = cb + jj;
            if (p == rB) continue;
            const float s = fmaxf(Pf[L8[jj]] + Sf[R8[jj]], 1e-38f);
            lnsumB += (double)(MBB + __logf(s));
        }
    }

    // ---- reductions (both rows) ----
    #pragma unroll
    for (int st = 32; st > 0; st >>= 1) {
        dsumA  += __shfl_down(dsumA, st);
        lnsumA += __shfl_down(lnsumA, st);
        dsumB  += __shfl_down(dsumB, st);
        lnsumB += __shfl_down(lnsumB, st);
    }
    if (lane == 0) { wDA[w] = dsumA; wLA[w] = lnsumA; wDB[w] = dsumB; wLB[w] = lnsumB; }
    __syncthreads();   // B9
    if (t == 0) {
        rowval[rA] = (-(wDA[0] + wDA[1] + wDA[2] + wDA[3]) / 0.07)
                   - (wLA[0] + wLA[1] + wLA[2] + wLA[3]);
        rowval[rB] = (-(wDB[0] + wDB[1] + wDB[2] + wDB[3]) / 0.07)
                   - (wLB[0] + wLB[1] + wLB[2] + wLB[3]);
    }
}

// ---------------- kernel 4: final mean ----------------
__global__ __launch_bounds__(256) void finalize_kernel(const double* __restrict__ rowval,
                                                       float* __restrict__ out) {
    __shared__ double red[NT];
    const int t = threadIdx.x;
    double s = 0.0;
    for (int j = t; j < NN; j += NT) s += rowval[j];
    red[t] = s;
    __syncthreads();
    for (int ofs = NT / 2; ofs > 0; ofs >>= 1) {
        if (t < ofs) red[t] += red[t + ofs];
        __syncthreads();
    }
    if (t == 0) {
        out[0] = (float)(-red[0] / ((double)NN * (double)(NN - 1)));
    }
}

extern "C" void kernel_launch(void* const* d_in, const int* in_sizes, int n_in,
                              void* d_out, int out_size, void* d_ws, size_t ws_size,
                              hipStream_t stream) {
    const float* features = (const float*)d_in[0];  // [1024, 2, 512] fp32
    const float* labels   = (const float*)d_in[1];  // [1024] fp32
    float* out = (float*)d_out;

    char* ws = (char*)d_ws;
    size_t off = 0;
    float*  sq     = (float*) (ws + off); off += NN * sizeof(float);
    float*  slab   = (float*) (ws + off); off += NN * sizeof(float);
    int*    sj     = (int*)   (ws + off); off += NN * sizeof(int);
    double* rowval = (double*)(ws + off); off += NN * sizeof(double);
    ushort* Ahi    = (ushort*)(ws + off); off += (size_t)NN * DD * sizeof(ushort);
    ushort* Alo    = (ushort*)(ws + off); off += (size_t)NN * DD * sizeof(ushort);
    float*  distp  = (float*) (ws + off); off += (size_t)NN * NN * sizeof(float);

    sort_labels_kernel<<<1, 512, 0, stream>>>(labels, slab, sj);
    prep_split_kernel<<<NN / 4, NT, 0, stream>>>(features, Ahi, Alo, sq);
    gemm_dist_kernel<<<16 * 17, NT, 0, stream>>>(Ahi, Alo, sq, sj, distp);  // 272 lower tiles
    row_kernel<<<NN / 2, NT, 0, stream>>>(distp, slab, rowval);
    finalize_kernel<<<1, NT, 0, stream>>>(rowval, out);
}